// Round 7
// baseline (258.601 us; speedup 1.0000x reference)
//
#include <hip/hip_runtime.h>
#include <hip/hip_cooperative_groups.h>
#include <hip/hip_bf16.h>
#include <cstdint>
#include <cstddef>

namespace cg = cooperative_groups;

// Problem constants (B=2, N=2048, D=1024, H=16, DH=64, window +-64)
#define BB 2
#define NN 2048
#define DD 1024
#define HH 16
#define DHH 64
#define SCALE 0.125f

typedef _Float16 f16x8 __attribute__((ext_vector_type(8)));
typedef _Float16 f16x4 __attribute__((ext_vector_type(4)));
typedef float f32x4 __attribute__((ext_vector_type(4)));

#define AS1(p) ((__attribute__((address_space(1))) void*)(p))
#define AS3(p) ((__attribute__((address_space(3))) void*)(p))

// ---------------- QKV GEMM body (v6, verified R6): 256x256, 2-phase/K-tile, counted vmcnt ----------------
template <bool SWAP>
__device__ __forceinline__ void qkv_body(const _Float16* __restrict__ A,
                                         const _Float16* __restrict__ Bt,
                                         const float* __restrict__ bias,
                                         _Float16* __restrict__ q_h,
                                         _Float16* __restrict__ k_h,
                                         _Float16* __restrict__ vt_h,
                                         _Float16* As, _Float16* Bs,
                                         int bm, int bn, int region) {
    (void)region;
    int tid = threadIdx.x;
    int wave = tid >> 6, lane = tid & 63;
    int llo = lane & 15, lhi = lane >> 4;
    int wm = (wave >> 2) * 128, wn = (wave & 3) * 64;   // per-wave 128x64 output tile
    int l8 = lane >> 3;
    int gchunk = ((lane & 7) ^ l8) * 8;                 // inverse-swizzled source chunk

    int rAu = wm + (wave & 3) * 16;
    int rBu = (wave >> 1) * 64 + (wave & 1) * 16;
    const _Float16* gA = A + (size_t)(bm + rAu + l8) * DD + gchunk;
    const _Float16* gB = Bt + (size_t)(bn + rBu + l8) * DD + gchunk;
    _Float16* lA = As + rAu * 64 + lane * 8;
    _Float16* lB = Bs + rBu * 64 + lane * 8;

#define STA(H, C, T, U) __builtin_amdgcn_global_load_lds( \
        AS1(gA + (size_t)((H) * 64 + (C) * 8) * DD + (T) * 64), \
        AS3(lA + (U) * 16384 + ((H) * 64 + (C) * 8) * 64), 16, 0, 0)
#define STB(H, C, T, U) __builtin_amdgcn_global_load_lds( \
        AS1(gB + (size_t)((H) * 32 + (C) * 8) * DD + (T) * 64), \
        AS3(lB + (U) * 16384 + ((H) * 32 + (C) * 8) * 64), 16, 0, 0)
#define RDA(MT, KS, U) (*(const f16x8*)(As + (U) * 16384 + (wm + (MT) * 16 + llo) * 64 + ((((KS) * 4 + lhi) ^ (llo & 7)) * 8)))
#define RDB(NT, KS, U) (*(const f16x8*)(Bs + (U) * 16384 + (wn + (NT) * 16 + llo) * 64 + ((((KS) * 4 + lhi) ^ (llo & 7)) * 8)))
#define MM(MT, NT, KS) do { \
        if constexpr (SWAP) acc[NT][MT] = __builtin_amdgcn_mfma_f32_16x16x32_f16(bf[NT][KS], af[(MT) & 3][KS], acc[NT][MT], 0, 0, 0); \
        else acc[MT][NT] = __builtin_amdgcn_mfma_f32_16x16x32_f16(af[(MT) & 3][KS], bf[NT][KS], acc[MT][NT], 0, 0, 0); \
    } while (0)

    f32x4 acc[SWAP ? 4 : 8][SWAP ? 8 : 4] = {};
    f16x8 af[4][2], bf[4][2];

    STA(0, 0, 0, 0); STA(0, 1, 0, 0);     // A0
    STB(0, 0, 0, 0); STB(0, 1, 0, 0);     // B0
    STB(1, 0, 0, 0); STB(1, 1, 0, 0);     // B1
    STA(1, 0, 0, 0); STA(1, 1, 0, 0);     // A1
    asm volatile("s_waitcnt vmcnt(2)" ::: "memory");   // A0,B0,B1 landed; A1 in flight
    __builtin_amdgcn_s_barrier();

#pragma unroll 1
    for (int t = 0; t < 15; ++t) {
        int u = t & 1, nu = u ^ 1;
        // ---- P1: read A0 + B0,B1; stage A0',B0',B1' (6 loads); 32 MFMA
#pragma unroll
        for (int mt = 0; mt < 4; ++mt) { af[mt][0] = RDA(mt, 0, u); af[mt][1] = RDA(mt, 1, u); }
#pragma unroll
        for (int nt = 0; nt < 4; ++nt) { bf[nt][0] = RDB(nt, 0, u); bf[nt][1] = RDB(nt, 1, u); }
        STA(0, 0, t + 1, nu); STA(0, 1, t + 1, nu);
        STB(0, 0, t + 1, nu); STB(0, 1, t + 1, nu);
        STB(1, 0, t + 1, nu); STB(1, 1, t + 1, nu);
        __builtin_amdgcn_s_barrier();
        asm volatile("s_waitcnt lgkmcnt(0)" ::: "memory");
        __builtin_amdgcn_s_setprio(1);
#pragma unroll
        for (int ks = 0; ks < 2; ++ks)
#pragma unroll
            for (int mt = 0; mt < 4; ++mt) { MM(mt, 0, ks); MM(mt, 1, ks); MM(mt, 2, ks); MM(mt, 3, ks); }
        __builtin_amdgcn_s_setprio(0);
        asm volatile("s_waitcnt vmcnt(6)" ::: "memory");   // A1(t) landed
        __builtin_amdgcn_s_barrier();
        // ---- P2: read A1; stage A1' (2 loads); 32 MFMA
#pragma unroll
        for (int mt = 0; mt < 4; ++mt) { af[mt][0] = RDA(mt + 4, 0, u); af[mt][1] = RDA(mt + 4, 1, u); }
        STA(1, 0, t + 1, nu); STA(1, 1, t + 1, nu);
        __builtin_amdgcn_s_barrier();
        asm volatile("s_waitcnt lgkmcnt(0)" ::: "memory");
        __builtin_amdgcn_s_setprio(1);
#pragma unroll
        for (int ks = 0; ks < 2; ++ks)
#pragma unroll
            for (int mt = 4; mt < 8; ++mt) { MM(mt, 0, ks); MM(mt, 1, ks); MM(mt, 2, ks); MM(mt, 3, ks); }
        __builtin_amdgcn_s_setprio(0);
        asm volatile("s_waitcnt vmcnt(2)" ::: "memory");   // A0',B0',B1'(t+1) landed
        __builtin_amdgcn_s_barrier();
    }

    // ---- peeled K-tile 15 (buf 1): drain 2 -> 0
    {
#pragma unroll
        for (int mt = 0; mt < 4; ++mt) { af[mt][0] = RDA(mt, 0, 1); af[mt][1] = RDA(mt, 1, 1); }
#pragma unroll
        for (int nt = 0; nt < 4; ++nt) { bf[nt][0] = RDB(nt, 0, 1); bf[nt][1] = RDB(nt, 1, 1); }
        asm volatile("s_waitcnt lgkmcnt(0)" ::: "memory");
        __builtin_amdgcn_s_setprio(1);
#pragma unroll
        for (int ks = 0; ks < 2; ++ks)
#pragma unroll
            for (int mt = 0; mt < 4; ++mt) { MM(mt, 0, ks); MM(mt, 1, ks); MM(mt, 2, ks); MM(mt, 3, ks); }
        __builtin_amdgcn_s_setprio(0);
        asm volatile("s_waitcnt vmcnt(0)" ::: "memory");   // A1(15) landed
        __builtin_amdgcn_s_barrier();
#pragma unroll
        for (int mt = 0; mt < 4; ++mt) { af[mt][0] = RDA(mt + 4, 0, 1); af[mt][1] = RDA(mt + 4, 1, 1); }
        asm volatile("s_waitcnt lgkmcnt(0)" ::: "memory");
        __builtin_amdgcn_s_setprio(1);
#pragma unroll
        for (int ks = 0; ks < 2; ++ks)
#pragma unroll
            for (int mt = 4; mt < 8; ++mt) { MM(mt, 0, ks); MM(mt, 1, ks); MM(mt, 2, ks); MM(mt, 3, ks); }
        __builtin_amdgcn_s_setprio(0);
    }

    // ---- epilogue v5: LDS-restaged coalesced stores (verified R5/R6) ----
    __builtin_amdgcn_s_barrier();
    _Float16* R = (wave < 4) ? (As + wave * 8192) : (Bs + (wave - 4) * 8192);  // 16 KB/wave
    int bq = bm >> 11;
    int nb = (bm & 2047) + wm;

    if constexpr (SWAP) {
#pragma unroll
        for (int nt = 0; nt < 4; ++nt) {
            int fb = nt * 16 + lhi * 4;
            f32x4 b4 = *(const f32x4*)(bias + bn + wn + fb);
            int chunk = fb >> 3, off = fb & 7;
#pragma unroll
            for (int mt = 0; mt < 8; ++mt) {
                int t = mt * 16 + llo;
                f16x4 v4;
#pragma unroll
                for (int r = 0; r < 4; ++r) v4[r] = (_Float16)(acc[nt][mt][r] + b4[r]);
                *(f16x4*)(R + t * 64 + ((chunk ^ (t & 7)) << 3) + off) = v4;
            }
        }
        asm volatile("s_waitcnt lgkmcnt(0)" ::: "memory");
        _Float16* dst0 = (region == 0 ? q_h : k_h);
        int cb = (bn & 1023) + wn;
#pragma unroll
        for (int it = 0; it < 16; ++it) {
            int t = it * 8 + l8;
            f16x8 v = *(const f16x8*)(R + t * 64 + (((lane & 7) ^ (t & 7)) << 3));
            *(f16x8*)(dst0 + (size_t)(bq * NN + nb + t) * DD + cb + (lane & 7) * 8) = v;
        }
    } else {
#pragma unroll
        for (int nt = 0; nt < 4; ++nt) {
            int f = nt * 16 + llo;
            float bv = bias[bn + wn + f];
#pragma unroll
            for (int mt = 0; mt < 8; ++mt) {
                int tb = mt * 16 + lhi * 4;
                int chunk = tb >> 3, off = tb & 7;
                int slot = (chunk & 8) | ((chunk & 7) ^ (f & 7));
                f16x4 v4;
#pragma unroll
                for (int r = 0; r < 4; ++r) v4[r] = (_Float16)(acc[mt][nt][r] + bv);
                *(f16x4*)(R + f * 128 + (slot << 3) + off) = v4;
            }
        }
        asm volatile("s_waitcnt lgkmcnt(0)" ::: "memory");
        int cb = (bn & 1023) + wn;
#pragma unroll
        for (int it = 0; it < 16; ++it) {
            int f = it * 4 + lhi;
            int chunk = llo;
            int slot = (chunk & 8) | ((chunk & 7) ^ (f & 7));
            f16x8 v = *(const f16x8*)(R + f * 128 + (slot << 3));
            int c = cb + f;
            int h = c >> 6, dh = c & 63;
            *(f16x8*)(vt_h + ((size_t)((bq * HH + h) * DHH + dh)) * NN + nb + chunk * 8) = v;
        }
    }
#undef STA
#undef STB
#undef RDA
#undef RDB
#undef MM
}

// ---------------- attn tile body (R3-verified: QBLK=128, 8 waves) ----------------
#define PP2 168
#define VP2 280
__device__ __forceinline__ void attn_tile(int id, _Float16* smem,
                                          const _Float16* __restrict__ q_h,
                                          const _Float16* __restrict__ k_h,
                                          const _Float16* __restrict__ vt_h,
                                          _Float16* __restrict__ outh) {
    _Float16* Ks = smem;                 // 128*PP2 = 21504 f16 (43008 B), overlaid by P
    _Float16* Ps = smem;
    _Float16* Vt = smem + 21504;         // 64*VP2 = 17920 f16 (35840 B)
    int tid = threadIdx.x;
    int xcd = id & 7, j = id >> 3;
    int i0 = (xcd * 2 + (j & 1)) * 128;
    int hb = j >> 1;
    int h = hb & 15, b = hb >> 4;

    int wave = tid >> 6, lane = tid & 63;
    int llo = lane & 15, lhi = lane >> 4;

    // --- async K staging: rows jj = i0-64 .. i0+191 (OOR rows: garbage, masked later) ---
    {
        int srow = lane >> 3;
        int chunk = ((lane & 7) ^ (lane >> 3)) * 8;
        const _Float16* kb = k_h + (size_t)(b * NN) * DD + h * DHH + chunk;
#pragma unroll
        for (int q = 0; q < 4; ++q) {
            int p = wave * 4 + q;
            int jj = i0 - 64 + p * 8 + srow;
            __builtin_amdgcn_global_load_lds(AS1(kb + (ptrdiff_t)jj * DD), AS3(Ks + p * 512 + lane * 8), 16, 0, 0);
        }
    }

    // --- V^T staging: 64 dh-rows x 256 tokens; zero pad cols 256..279 ---
    {
        const _Float16* vb = vt_h + (size_t)((b * HH + h) * DHH) * NN + (i0 - 64);
#pragma unroll
        for (int u = tid; u < 2048; u += 512) {
            int d = u >> 5, c = u & 31;
            f16x8 vv = *(const f16x8*)(vb + (ptrdiff_t)d * NN + c * 8);
            *(f16x8*)(Vt + d * VP2 + c * 8) = vv;
        }
        if (tid < 192) {
            int d = tid / 3, c = tid % 3;
            f16x8 z = {};
            *(f16x8*)(Vt + d * VP2 + 256 + c * 8) = z;
        }
    }

    // --- Q fragments straight from global ---
    int qrow = wave * 16 + llo;
    int qi = i0 + qrow;
    const _Float16* qp = q_h + (size_t)(b * NN + qi) * DD + h * DHH;
    f16x8 qf0 = *(const f16x8*)(qp + lhi * 8);
    f16x8 qf1 = *(const f16x8*)(qp + 32 + lhi * 8);
    __syncthreads();

    // --- S^T = K @ Q^T over the wave's 9 visible key-tiles ---
    float sc[9][4];
#pragma unroll
    for (int mtl = 0; mtl < 9; ++mtl) {
        const _Float16* kr = Ks + ((wave + mtl) * 16 + llo) * 64;
        f16x8 kf0 = *(const f16x8*)(kr + ((lhi ^ (llo & 7)) * 8));
        f16x8 kf1 = *(const f16x8*)(kr + (((lhi + 4) ^ (llo & 7)) * 8));
        f32x4 a = {0.f, 0.f, 0.f, 0.f};
        a = __builtin_amdgcn_mfma_f32_16x16x32_f16(kf0, qf0, a, 0, 0, 0);
        a = __builtin_amdgcn_mfma_f32_16x16x32_f16(kf1, qf1, a, 0, 0, 0);
#pragma unroll
        for (int r = 0; r < 4; ++r) sc[mtl][r] = a[r];
    }
    __syncthreads();   // all waves done reading Ks; its LDS is now P's

    // --- masked softmax over the wave's 144 slots for query qi ---
    float m = -1e30f;
#pragma unroll
    for (int mtl = 0; mtl < 9; ++mtl)
#pragma unroll
        for (int r = 0; r < 4; ++r) {
            int sidx = (wave + mtl) * 16 + lhi * 4 + r;
            int jj = i0 - 64 + sidx;
            int dj = jj - qi;
            bool valid = (jj >= 0) && (jj < NN) && (dj <= 64) && (dj >= -64);
            float v = valid ? sc[mtl][r] * SCALE : -1e30f;
            sc[mtl][r] = v;
            m = fmaxf(m, v);
        }
    m = fmaxf(m, __shfl_xor(m, 16, 64));
    m = fmaxf(m, __shfl_xor(m, 32, 64));
    float l = 0.f;
#pragma unroll
    for (int mtl = 0; mtl < 9; ++mtl)
#pragma unroll
        for (int r = 0; r < 4; ++r) {
            float e = __expf(sc[mtl][r] - m);
            sc[mtl][r] = e;
            l += e;
        }
    l += __shfl_xor(l, 16, 64);
    l += __shfl_xor(l, 32, 64);
    float invl = 1.f / l;

    // --- write normalized P rows; pad cols 144..159 = 0 ---
#pragma unroll
    for (int mtl = 0; mtl < 9; ++mtl) {
        f16x4 pv;
#pragma unroll
        for (int r = 0; r < 4; ++r) pv[r] = (_Float16)(sc[mtl][r] * invl);
        *(f16x4*)(Ps + qrow * PP2 + mtl * 16 + lhi * 4) = pv;
    }
    {
        f16x4 z4 = {};
        *(f16x4*)(Ps + qrow * PP2 + 144 + lhi * 4) = z4;
    }
    __asm__ volatile("s_waitcnt lgkmcnt(0)" ::: "memory");

    // --- O = P @ V (V cols shifted by wave*16) ---
    f32x4 oacc[4] = {};
#pragma unroll
    for (int ks = 0; ks < 5; ++ks) {
        f16x8 pf = *(const f16x8*)(Ps + qrow * PP2 + ks * 32 + lhi * 8);
#pragma unroll
        for (int nt = 0; nt < 4; ++nt) {
            f16x8 vf = *(const f16x8*)(Vt + (nt * 16 + llo) * VP2 + wave * 16 + ks * 32 + lhi * 8);
            oacc[nt] = __builtin_amdgcn_mfma_f32_16x16x32_f16(pf, vf, oacc[nt], 0, 0, 0);
        }
    }

    // --- epilogue ---
    _Float16* orow = outh + (size_t)(b * NN) * DD + h * DHH;
#pragma unroll
    for (int nt = 0; nt < 4; ++nt)
#pragma unroll
        for (int r = 0; r < 4; ++r) {
            int q = wave * 16 + lhi * 4 + r;
            int d = nt * 16 + llo;
            orow[(size_t)(i0 + q) * DD + d] = (_Float16)oacc[nt][r];
        }
}

// ---------------- fused megakernel: prep -> qkv -> attn -> out with grid.sync ----------------
__global__ __launch_bounds__(512, 2) void fused(const float* __restrict__ x,
                                                const float* __restrict__ Wqkv,
                                                const float* __restrict__ bqkv,
                                                const float* __restrict__ Wout,
                                                const float* __restrict__ bout,
                                                float* __restrict__ out,
                                                _Float16* __restrict__ x_h,
                                                _Float16* __restrict__ Wqkv_t,
                                                _Float16* __restrict__ Wout_t,
                                                _Float16* __restrict__ q_h,
                                                _Float16* __restrict__ k_h,
                                                _Float16* __restrict__ vt_h,
                                                _Float16* __restrict__ attn_h) {
    __shared__ __align__(16) _Float16 smem[65536];   // 128 KiB, re-aliased per stage
    cg::grid_group grid = cg::this_grid();
    int bid = blockIdx.x, tid = threadIdx.x;

    // ================= Stage P: x cast + weight transposes =================
    {
        // cast: 4096x1024 f32 -> f16, grid-stride (524288 f16x8 units / 131072 threads = 4)
        for (int u = bid * 512 + tid; u < 524288; u += 256 * 512) {
            int i = u * 8;
            f32x4 a = *(const f32x4*)(x + i);
            f32x4 b = *(const f32x4*)(x + i + 4);
            f16x8 o;
            o[0] = (_Float16)a[0]; o[1] = (_Float16)a[1]; o[2] = (_Float16)a[2]; o[3] = (_Float16)a[3];
            o[4] = (_Float16)b[0]; o[5] = (_Float16)b[1]; o[6] = (_Float16)b[2]; o[7] = (_Float16)b[3];
            *(f16x8*)(x_h + i) = o;
        }
        // transposes: 4096 32x32-tile units (3072 Wqkv + 1024 Wout), 16/block = 8 iters x 2 halves
        float* ftile = (float*)smem;                  // 2 x [32][33] f32 = 8448 B
        int half = tid >> 8, t2 = tid & 255;
        int txx = t2 & 31, ty = t2 >> 5;
        float* T = ftile + half * (32 * 33);
        for (int it = 0; it < 8; ++it) {
            int u = bid * 16 + it * 2 + half;
            const float* in; _Float16* outp; int C, tc, tr;
            if (u < 3072) { C = 3 * DD; in = Wqkv; outp = Wqkv_t; tc = u % 96; tr = u / 96; }
            else { int v = u - 3072; C = DD; in = Wout; outp = Wout_t; tc = v % 32; tr = v / 32; }
            int r0 = tr * 32, c0 = tc * 32;
            __syncthreads();
#pragma unroll
            for (int i = 0; i < 32; i += 8)
                T[(ty + i) * 33 + txx] = in[(size_t)(r0 + ty + i) * C + (c0 + txx)];
            __syncthreads();
#pragma unroll
            for (int i = 0; i < 32; i += 8)
                outp[(size_t)(c0 + ty + i) * DD + (r0 + txx)] = (_Float16)T[txx * 33 + (ty + i)];
        }
    }
    grid.sync();

    // ================= Stage Q: QKV GEMM (blocks 0..191) =================
    if (bid < 192) {
        int xcd = bid & 7, jj = bid >> 3;
        int mtile = (xcd >> 1) * 4 + jj / 6;
        int ntile = (xcd & 1) * 6 + jj % 6;
        int bm = mtile * 256, bn = ntile * 256;
        int region = bn >> 10;
        if (region == 2)
            qkv_body<false>(x_h, Wqkv_t, bqkv, q_h, k_h, vt_h, smem, smem + 32768, bm, bn, region);
        else
            qkv_body<true>(x_h, Wqkv_t, bqkv, q_h, k_h, vt_h, smem, smem + 32768, bm, bn, region);
    }
    grid.sync();

    // ================= Stage A: windowed attention (512 tiles, 2/block) =================
    for (int it = 0; it < 2; ++it) {
        __syncthreads();                   // protect LDS reuse across iterations
        attn_tile(bid + it * 256, smem, q_h, k_h, vt_h, attn_h);
    }
    grid.sync();

    // ================= Stage O: out-proj GEMM (256 tiles, 1/block, 128x128) =================
    {
        _Float16* OAs = smem;              // [128][64] = 16 KB
        _Float16* OBs = smem + 8192;       // [128][64] = 16 KB
        int xcd = bid & 7, j = bid >> 3;
        int bm = (xcd * 4 + (j >> 3)) * 128;
        int bn = (j & 7) * 128;
        int wave = tid >> 6, lane = tid & 63;
        int wm = (wave >> 2) * 64, wn = (wave & 3) * 32;
        int lhi = lane >> 4, llo = lane & 15;

        f32x4 acc[2][4] = {};   // [nt][mt] (SWAP orientation)

        int srow = wave * 16 + (lane >> 3);
        int scol = ((lane & 7) ^ (lane >> 3)) * 8;
        const _Float16* gA = attn_h + (size_t)(bm + srow) * DD + scol;
        const _Float16* gB = Wout_t + (size_t)(bn + srow) * DD + scol;
        _Float16* lA = OAs + wave * 1024 + lane * 8;
        _Float16* lB = OBs + wave * 1024 + lane * 8;

        for (int k0 = 0; k0 < DD; k0 += 64) {
            __syncthreads();
#pragma unroll
            for (int p = 0; p < 2; ++p) {
                __builtin_amdgcn_global_load_lds(AS1(gA + (size_t)p * 8 * DD + k0), AS3(lA + p * 512), 16, 0, 0);
                __builtin_amdgcn_global_load_lds(AS1(gB + (size_t)p * 8 * DD + k0), AS3(lB + p * 512), 16, 0, 0);
            }
            __syncthreads();
#pragma unroll
            for (int ks = 0; ks < 2; ++ks) {
                f16x8 af[4], bf[2];
                int swz = (((ks * 4 + lhi) ^ (llo & 7)) * 8);
#pragma unroll
                for (int mt = 0; mt < 4; ++mt)
                    af[mt] = *(const f16x8*)(OAs + (wm + mt * 16 + llo) * 64 + swz);
#pragma unroll
                for (int nt = 0; nt < 2; ++nt)
                    bf[nt] = *(const f16x8*)(OBs + (wn + nt * 16 + llo) * 64 + swz);
#pragma unroll
                for (int nt = 0; nt < 2; ++nt)
#pragma unroll
                    for (int mt = 0; mt < 4; ++mt)
                        acc[nt][mt] = __builtin_amdgcn_mfma_f32_16x16x32_f16(bf[nt], af[mt], acc[nt][mt], 0, 0, 0);
            }
        }

#pragma unroll
        for (int nt = 0; nt < 2; ++nt) {
            int cbase = bn + wn + nt * 16 + lhi * 4;
            f32x4 b4 = *(const f32x4*)(bout + cbase);
#pragma unroll
            for (int mt = 0; mt < 4; ++mt) {
                int t = bm + wm + mt * 16 + llo;
                f32x4 v4;
#pragma unroll
                for (int r = 0; r < 4; ++r) v4[r] = acc[nt][mt][r] + b4[r];
                *(f32x4*)(out + (size_t)t * DD + cbase) = v4;
            }
        }
    }
}

// ---------------- launch ----------------
extern "C" void kernel_launch(void* const* d_in, const int* in_sizes, int n_in,
                              void* d_out, int out_size, void* d_ws, size_t ws_size,
                              hipStream_t stream) {
    const float* x    = (const float*)d_in[0];
    const float* Wqkv = (const float*)d_in[1];
    const float* bqkv = (const float*)d_in[2];
    const float* Wout = (const float*)d_in[3];
    const float* bout = (const float*)d_in[4];
    float* out = (float*)d_out;

    char* ws = (char*)d_ws;
    _Float16* x_h    = (_Float16*)(ws);                              //  8 MB [4096][1024]
    _Float16* Wqkv_t = (_Float16*)(ws + (size_t)8  * 1024 * 1024);   //  6 MB [3072][1024]
    _Float16* Wout_t = (_Float16*)(ws + (size_t)14 * 1024 * 1024);   //  2 MB [1024][1024]
    _Float16* q_h    = (_Float16*)(ws + (size_t)16 * 1024 * 1024);   //  8 MB [2][2048][1024]
    _Float16* k_h    = (_Float16*)(ws + (size_t)24 * 1024 * 1024);   //  8 MB [2][2048][1024]
    _Float16* vt_h   = (_Float16*)(ws + (size_t)32 * 1024 * 1024);   //  8 MB [2*16*64][2048]
    _Float16* attn_h = (_Float16*)(ws + (size_t)40 * 1024 * 1024);   //  8 MB [4096][1024]

    void* args[] = {(void*)&x, (void*)&Wqkv, (void*)&bqkv, (void*)&Wout, (void*)&bout,
                    (void*)&out, (void*)&x_h, (void*)&Wqkv_t, (void*)&Wout_t,
                    (void*)&q_h, (void*)&k_h, (void*)&vt_h, (void*)&attn_h};
    hipLaunchCooperativeKernel((void*)fused, dim3(256), dim3(512), args, 0, stream);
}

// Round 8
// 151.481 us; speedup vs baseline: 1.7072x; 1.7072x over previous
//
#include <hip/hip_runtime.h>
#include <hip/hip_bf16.h>
#include <cstdint>
#include <cstddef>

// Problem constants (B=2, N=2048, D=1024, H=16, DH=64, window +-64)
#define BB 2
#define NN 2048
#define DD 1024
#define HH 16
#define DHH 64
#define SCALE 0.125f

typedef _Float16 f16x8 __attribute__((ext_vector_type(8)));
typedef _Float16 f16x4 __attribute__((ext_vector_type(4)));
typedef float f32x4 __attribute__((ext_vector_type(4)));

#define AS1(p) ((__attribute__((address_space(1))) void*)(p))
#define AS3(p) ((__attribute__((address_space(3))) void*)(p))

// ---------------- fused prep: x cast + both weight transposes, one launch ----------------
__global__ __launch_bounds__(256) void prep(const float* __restrict__ x, _Float16* __restrict__ x_h,
                                            const float* __restrict__ Wqkv, _Float16* __restrict__ Wqkv_t,
                                            const float* __restrict__ Wout, _Float16* __restrict__ Wout_t) {
    __shared__ float tile[32][33];
    int bx = blockIdx.x, tid = threadIdx.x;
    if (bx < 2048) {
        int i = bx * 2048 + tid * 8;
        f32x4 a = *(const f32x4*)(x + i);
        f32x4 b = *(const f32x4*)(x + i + 4);
        f16x8 o;
        o[0] = (_Float16)a[0]; o[1] = (_Float16)a[1]; o[2] = (_Float16)a[2]; o[3] = (_Float16)a[3];
        o[4] = (_Float16)b[0]; o[5] = (_Float16)b[1]; o[6] = (_Float16)b[2]; o[7] = (_Float16)b[3];
        *(f16x8*)(x_h + i) = o;
        return;
    }
    const float* in; _Float16* out; int C, tc, tr;
    if (bx < 5120) { int t = bx - 2048; C = 3 * DD; in = Wqkv; out = Wqkv_t; tc = t % 96; tr = t / 96; }
    else           { int t = bx - 5120; C = DD;     in = Wout; out = Wout_t; tc = t % 32; tr = t / 32; }
    int R = DD;
    int txx = tid & 31, ty = tid >> 5;
    int r0 = tr * 32, c0 = tc * 32;
#pragma unroll
    for (int i = 0; i < 32; i += 8)
        tile[ty + i][txx] = in[(size_t)(r0 + ty + i) * C + (c0 + txx)];
    __syncthreads();
#pragma unroll
    for (int i = 0; i < 32; i += 8)
        out[(size_t)(c0 + ty + i) * R + (r0 + txx)] = (_Float16)tile[txx][ty + i];
}

// ---------------- shared K-loop body (R6 family: single-buffer, BK=64, XOR-swizzled LDS) ----------------
// Used by gemm_out. LDS slot c_l of row r holds global chunk c_l^(r&7); staging lane L reads
// global chunk (L&7)^(L>>3) (wave/pass-invariant -> global_load_lds uniform-base-legal).
template <bool SWAP, int MT>
__device__ __forceinline__ void gemm_kloop(const _Float16* __restrict__ gA,
                                           const _Float16* __restrict__ gB,
                                           _Float16* lA, _Float16* lB,
                                           const _Float16* As, const _Float16* Bs,
                                           int wm, int wn, int llo, int lhi, int K,
                                           f32x4 acc[][MT > 4 ? MT : 4]) {
    for (int k0 = 0; k0 < K; k0 += 64) {
        __syncthreads();
#pragma unroll
        for (int p = 0; p < MT; ++p)
            __builtin_amdgcn_global_load_lds(AS1(gA + (size_t)p * 8 * K + k0), AS3(lA + p * 512), 16, 0, 0);
#pragma unroll
        for (int p = 0; p < 4; ++p)
            __builtin_amdgcn_global_load_lds(AS1(gB + (size_t)p * 8 * K + k0), AS3(lB + p * 512), 16, 0, 0);
        __syncthreads();

#pragma unroll
        for (int ks = 0; ks < 2; ++ks) {
            f16x8 af[MT], bf[4];
            int swz = (((ks * 4 + lhi) ^ (llo & 7)) * 8);
#pragma unroll
            for (int mt = 0; mt < MT; ++mt)
                af[mt] = *(const f16x8*)(As + (wm + mt * 16 + llo) * 64 + swz);
#pragma unroll
            for (int nt = 0; nt < 4; ++nt)
                bf[nt] = *(const f16x8*)(Bs + (wn + nt * 16 + llo) * 64 + swz);
            if (SWAP) {
#pragma unroll
                for (int nt = 0; nt < 4; ++nt)
#pragma unroll
                    for (int mt = 0; mt < MT; ++mt)
                        acc[nt][mt] = __builtin_amdgcn_mfma_f32_16x16x32_f16(bf[nt], af[mt], acc[nt][mt], 0, 0, 0);
            } else {
#pragma unroll
                for (int mt = 0; mt < MT; ++mt)
#pragma unroll
                    for (int nt = 0; nt < 4; ++nt)
                        acc[mt][nt] = __builtin_amdgcn_mfma_f32_16x16x32_f16(af[mt], bf[nt], acc[mt][nt], 0, 0, 0);
            }
        }
    }
}

// ---------------- QKV GEMM v6: 256x256, 2-phase/K-tile, FIFO-minimal counted vmcnt ----------------
// P1: read A0 (mt0-3) + B0,B1 (nt0-3); stage A0',B0',B1' (6 loads); 32 MFMA.
// P2: read A1 (mt4-7); stage A1' (2 loads); 32 MFMA.
// Ledger (steady state, outstanding 8): P1-end vmcnt(6) [A1(t), issued P2(t-1)];
// P2-end vmcnt(2) [A0'B0'B1'(t+1), issued P1(t)]. Peel drains 2 -> 0.
// Epilogue v5: LDS-restaged coalesced stores (verified R5/R6).
template <bool SWAP>
__device__ __forceinline__ void qkv_body(const _Float16* __restrict__ A,
                                         const _Float16* __restrict__ Bt,
                                         const float* __restrict__ bias,
                                         _Float16* __restrict__ q_h,
                                         _Float16* __restrict__ k_h,
                                         _Float16* __restrict__ vt_h,
                                         _Float16* As, _Float16* Bs,
                                         int bm, int bn, int region) {
    (void)region;
    int tid = threadIdx.x;
    int wave = tid >> 6, lane = tid & 63;
    int llo = lane & 15, lhi = lane >> 4;
    int wm = (wave >> 2) * 128, wn = (wave & 3) * 64;   // per-wave 128x64 output tile
    int l8 = lane >> 3;
    int gchunk = ((lane & 7) ^ l8) * 8;                 // inverse-swizzled source chunk

    int rAu = wm + (wave & 3) * 16;                     // A staging row base: + h*64 + c*8 (+ l8)
    int rBu = (wave >> 1) * 64 + (wave & 1) * 16;       // B staging row base: + h*32 + c*8 (+ l8)
    const _Float16* gA = A + (size_t)(bm + rAu + l8) * DD + gchunk;
    const _Float16* gB = Bt + (size_t)(bn + rBu + l8) * DD + gchunk;
    _Float16* lA = As + rAu * 64 + lane * 8;
    _Float16* lB = Bs + rBu * 64 + lane * 8;

#define STA(H, C, T, U) __builtin_amdgcn_global_load_lds( \
        AS1(gA + (size_t)((H) * 64 + (C) * 8) * DD + (T) * 64), \
        AS3(lA + (U) * 16384 + ((H) * 64 + (C) * 8) * 64), 16, 0, 0)
#define STB(H, C, T, U) __builtin_amdgcn_global_load_lds( \
        AS1(gB + (size_t)((H) * 32 + (C) * 8) * DD + (T) * 64), \
        AS3(lB + (U) * 16384 + ((H) * 32 + (C) * 8) * 64), 16, 0, 0)
#define RDA(MT, KS, U) (*(const f16x8*)(As + (U) * 16384 + (wm + (MT) * 16 + llo) * 64 + ((((KS) * 4 + lhi) ^ (llo & 7)) * 8)))
#define RDB(NT, KS, U) (*(const f16x8*)(Bs + (U) * 16384 + (wn + (NT) * 16 + llo) * 64 + ((((KS) * 4 + lhi) ^ (llo & 7)) * 8)))
#define MM(MT, NT, KS) do { \
        if constexpr (SWAP) acc[NT][MT] = __builtin_amdgcn_mfma_f32_16x16x32_f16(bf[NT][KS], af[(MT) & 3][KS], acc[NT][MT], 0, 0, 0); \
        else acc[MT][NT] = __builtin_amdgcn_mfma_f32_16x16x32_f16(af[(MT) & 3][KS], bf[NT][KS], acc[MT][NT], 0, 0, 0); \
    } while (0)

    f32x4 acc[SWAP ? 4 : 8][SWAP ? 8 : 4] = {};
    f16x8 af[4][2], bf[4][2];

    // prologue: all 4 half-tiles of K-tile 0 into buf 0, FIFO order = consumption order
    STA(0, 0, 0, 0); STA(0, 1, 0, 0);     // A0
    STB(0, 0, 0, 0); STB(0, 1, 0, 0);     // B0
    STB(1, 0, 0, 0); STB(1, 1, 0, 0);     // B1
    STA(1, 0, 0, 0); STA(1, 1, 0, 0);     // A1
    asm volatile("s_waitcnt vmcnt(2)" ::: "memory");   // A0,B0,B1 landed; A1 in flight
    __builtin_amdgcn_s_barrier();

#pragma unroll 1
    for (int t = 0; t < 15; ++t) {
        int u = t & 1, nu = u ^ 1;
        // ---- P1: read A0 (mt0-3) + B0,B1 (nt0-3); stage A0',B0',B1' (6 loads); 32 MFMA
#pragma unroll
        for (int mt = 0; mt < 4; ++mt) { af[mt][0] = RDA(mt, 0, u); af[mt][1] = RDA(mt, 1, u); }
#pragma unroll
        for (int nt = 0; nt < 4; ++nt) { bf[nt][0] = RDB(nt, 0, u); bf[nt][1] = RDB(nt, 1, u); }
        STA(0, 0, t + 1, nu); STA(0, 1, t + 1, nu);
        STB(0, 0, t + 1, nu); STB(0, 1, t + 1, nu);
        STB(1, 0, t + 1, nu); STB(1, 1, t + 1, nu);
        __builtin_amdgcn_s_barrier();
        asm volatile("s_waitcnt lgkmcnt(0)" ::: "memory");
        __builtin_amdgcn_s_setprio(1);
#pragma unroll
        for (int ks = 0; ks < 2; ++ks)
#pragma unroll
            for (int mt = 0; mt < 4; ++mt) { MM(mt, 0, ks); MM(mt, 1, ks); MM(mt, 2, ks); MM(mt, 3, ks); }
        __builtin_amdgcn_s_setprio(0);
        asm volatile("s_waitcnt vmcnt(6)" ::: "memory");   // A1(t) landed (issued P2(t-1))
        __builtin_amdgcn_s_barrier();
        // ---- P2: read A1 (mt4-7); stage A1' (2 loads); 32 MFMA
#pragma unroll
        for (int mt = 0; mt < 4; ++mt) { af[mt][0] = RDA(mt + 4, 0, u); af[mt][1] = RDA(mt + 4, 1, u); }
        STA(1, 0, t + 1, nu); STA(1, 1, t + 1, nu);
        __builtin_amdgcn_s_barrier();
        asm volatile("s_waitcnt lgkmcnt(0)" ::: "memory");
        __builtin_amdgcn_s_setprio(1);
#pragma unroll
        for (int ks = 0; ks < 2; ++ks)
#pragma unroll
            for (int mt = 4; mt < 8; ++mt) { MM(mt, 0, ks); MM(mt, 1, ks); MM(mt, 2, ks); MM(mt, 3, ks); }
        __builtin_amdgcn_s_setprio(0);
        asm volatile("s_waitcnt vmcnt(2)" ::: "memory");   // A0',B0',B1'(t+1) landed
        __builtin_amdgcn_s_barrier();
    }

    // ---- peeled K-tile 15 (buf 1): drain 2 -> 0
    {
#pragma unroll
        for (int mt = 0; mt < 4; ++mt) { af[mt][0] = RDA(mt, 0, 1); af[mt][1] = RDA(mt, 1, 1); }
#pragma unroll
        for (int nt = 0; nt < 4; ++nt) { bf[nt][0] = RDB(nt, 0, 1); bf[nt][1] = RDB(nt, 1, 1); }
        asm volatile("s_waitcnt lgkmcnt(0)" ::: "memory");
        __builtin_amdgcn_s_setprio(1);
#pragma unroll
        for (int ks = 0; ks < 2; ++ks)
#pragma unroll
            for (int mt = 0; mt < 4; ++mt) { MM(mt, 0, ks); MM(mt, 1, ks); MM(mt, 2, ks); MM(mt, 3, ks); }
        __builtin_amdgcn_s_setprio(0);
        asm volatile("s_waitcnt vmcnt(0)" ::: "memory");   // A1(15) landed
        __builtin_amdgcn_s_barrier();
#pragma unroll
        for (int mt = 0; mt < 4; ++mt) { af[mt][0] = RDA(mt + 4, 0, 1); af[mt][1] = RDA(mt + 4, 1, 1); }
        asm volatile("s_waitcnt lgkmcnt(0)" ::: "memory");
        __builtin_amdgcn_s_setprio(1);
#pragma unroll
        for (int ks = 0; ks < 2; ++ks)
#pragma unroll
            for (int mt = 4; mt < 8; ++mt) { MM(mt, 0, ks); MM(mt, 1, ks); MM(mt, 2, ks); MM(mt, 3, ks); }
        __builtin_amdgcn_s_setprio(0);
    }

    // ---- epilogue v5: LDS-restaged coalesced stores ----
    __builtin_amdgcn_s_barrier();      // all waves done with K-loop LDS reads; As/Bs now dead
    _Float16* R = (wave < 4) ? (As + wave * 8192) : (Bs + (wave - 4) * 8192);  // 16 KB/wave
    int bq = bm >> 11;                 // batch (256-tile never crosses n=2048)
    int nb = (bm & 2047) + wm;         // wave's first token within batch

    if constexpr (SWAP) {
        // acc[nt][mt]: token t = mt*16+llo, feature f = nt*16+lhi*4 (+r).
        // Restage as [tok 128][feat 64], chunk-swizzled: slot = (f>>3) ^ (t&7).
#pragma unroll
        for (int nt = 0; nt < 4; ++nt) {
            int fb = nt * 16 + lhi * 4;
            f32x4 b4 = *(const f32x4*)(bias + bn + wn + fb);
            int chunk = fb >> 3, off = fb & 7;          // off = 0 or 4
#pragma unroll
            for (int mt = 0; mt < 8; ++mt) {
                int t = mt * 16 + llo;
                f16x4 v4;
#pragma unroll
                for (int r = 0; r < 4; ++r) v4[r] = (_Float16)(acc[nt][mt][r] + b4[r]);
                *(f16x4*)(R + t * 64 + ((chunk ^ (t & 7)) << 3) + off) = v4;
            }
        }
        asm volatile("s_waitcnt lgkmcnt(0)" ::: "memory");   // wave-local write->read
        _Float16* dst0 = (region == 0 ? q_h : k_h);
        int cb = (bn & 1023) + wn;
#pragma unroll
        for (int it = 0; it < 16; ++it) {
            int t = it * 8 + l8;
            f16x8 v = *(const f16x8*)(R + t * 64 + (((lane & 7) ^ (t & 7)) << 3));
            *(f16x8*)(dst0 + (size_t)(bq * NN + nb + t) * DD + cb + (lane & 7) * 8) = v;
        }
    } else {
        // acc[mt][nt]: token t = mt*16+lhi*4 (+r), feature f = nt*16+llo.
        // Restage as [feat 64][tok 128]; slot = (chunk&8) | ((chunk&7)^(f&7)), chunk = t>>3.
#pragma unroll
        for (int nt = 0; nt < 4; ++nt) {
            int f = nt * 16 + llo;
            float bv = bias[bn + wn + f];
#pragma unroll
            for (int mt = 0; mt < 8; ++mt) {
                int tb = mt * 16 + lhi * 4;
                int chunk = tb >> 3, off = tb & 7;      // off = 0 or 4
                int slot = (chunk & 8) | ((chunk & 7) ^ (f & 7));
                f16x4 v4;
#pragma unroll
                for (int r = 0; r < 4; ++r) v4[r] = (_Float16)(acc[mt][nt][r] + bv);
                *(f16x4*)(R + f * 128 + (slot << 3) + off) = v4;
            }
        }
        asm volatile("s_waitcnt lgkmcnt(0)" ::: "memory");   // wave-local write->read
        int cb = (bn & 1023) + wn;
#pragma unroll
        for (int it = 0; it < 16; ++it) {
            int f = it * 4 + lhi;                        // feat-local 0..63
            int chunk = llo;                             // tok-chunk 0..15
            int slot = (chunk & 8) | ((chunk & 7) ^ (f & 7));
            f16x8 v = *(const f16x8*)(R + f * 128 + (slot << 3));
            int c = cb + f;
            int h = c >> 6, dh = c & 63;
            *(f16x8*)(vt_h + ((size_t)((bq * HH + h) * DHH + dh)) * NN + nb + chunk * 8) = v;
        }
    }
#undef STA
#undef STB
#undef RDA
#undef RDB
#undef MM
}

__global__ __launch_bounds__(512, 2) void gemm_qkv(const _Float16* __restrict__ A,
                                                   const _Float16* __restrict__ Bt,
                                                   const float* __restrict__ bias,
                                                   _Float16* __restrict__ q_h,
                                                   _Float16* __restrict__ k_h,
                                                   _Float16* __restrict__ vt_h) {
    __shared__ __align__(16) _Float16 As[2 * 16384];   // 64 KiB: 2 x [256][64]
    __shared__ __align__(16) _Float16 Bs[2 * 16384];   // 64 KiB
    int id = blockIdx.x;
    int xcd = id & 7, jj = id >> 3;                    // 8 XCD chunks of 24 tiles (4M x 6N)
    int mtile = (xcd >> 1) * 4 + jj / 6;
    int ntile = (xcd & 1) * 6 + jj % 6;
    int bm = mtile * 256, bn = ntile * 256;
    int region = bn >> 10;                             // block-uniform: 0=q, 1=k, 2=v
    if (region == 2)
        qkv_body<false>(A, Bt, bias, q_h, k_h, vt_h, As, Bs, bm, bn, region);
    else
        qkv_body<true>(A, Bt, bias, q_h, k_h, vt_h, As, Bs, bm, bn, region);
}

// ---------------- out-proj GEMM v2: 128x128 tile (R0-verified kloop<true,4> path) ----------------
__global__ __launch_bounds__(256) void gemm_out(const _Float16* __restrict__ A,
                                                const _Float16* __restrict__ Bt,
                                                const float* __restrict__ bias,
                                                float* __restrict__ Cf) {
    const int K = DD, N = DD;
    __shared__ __align__(16) _Float16 As[128 * 64];
    __shared__ __align__(16) _Float16 Bs[128 * 64];
    int id = blockIdx.x;
    int xcd = id & 7, j = id >> 3;            // 32 tiles per XCD chunk
    int bm = (xcd * 4 + (j >> 3)) * 128;      // 32 m-tiles = 8 xcd x 4
    int bn = (j & 7) * 128;                   // 8 n-tiles
    int tid = threadIdx.x;
    int wave = tid >> 6, lane = tid & 63;
    int wm = (wave >> 1) * 64, wn = (wave & 1) * 64;
    int lhi = lane >> 4, llo = lane & 15;

    f32x4 acc[4][4] = {};   // [nt][mt]

    int srow = wave * 32 + (lane >> 3);
    int scol = ((lane & 7) ^ (lane >> 3)) * 8;
    const _Float16* gA = A + (size_t)(bm + srow) * K + scol;
    const _Float16* gB = Bt + (size_t)(bn + srow) * K + scol;
    _Float16* lA = As + wave * 2048 + lane * 8;
    _Float16* lB = Bs + wave * 2048 + lane * 8;

    gemm_kloop<true, 4>(gA, gB, lA, lB, As, Bs, wm, wn, llo, lhi, K, acc);

#pragma unroll
    for (int nt = 0; nt < 4; ++nt) {
        int cbase = bn + wn + nt * 16 + lhi * 4;
        f32x4 b4 = *(const f32x4*)(bias + cbase);
#pragma unroll
        for (int mt = 0; mt < 4; ++mt) {
            int t = bm + wm + mt * 16 + llo;
            f32x4 v4;
#pragma unroll
            for (int r = 0; r < 4; ++r) v4[r] = acc[nt][mt][r] + b4[r];
            *(f32x4*)(Cf + (size_t)t * N + cbase) = v4;
        }
    }
}

// ---------------- windowed attention (R0-proven: QBLK=64, Ks/P LDS overlay, 3 blocks/CU) ----------------
#define KP 64
#define PP 200   // P stride: 400B (16B-aligned), rows 4 banks apart
#define VP 200
__global__ __launch_bounds__(256) void local_attn(const _Float16* __restrict__ q_h,
                                                  const _Float16* __restrict__ k_h,
                                                  const _Float16* __restrict__ vt_h,
                                                  _Float16* __restrict__ outh) {
    __shared__ __align__(16) _Float16 KsPs[64 * PP];  // 25600 B: Ks[192*64] overlaid by P[64*PP]
    __shared__ __align__(16) _Float16 Vt[64 * VP];    // 25600 B
    _Float16* Ks = KsPs;
    _Float16* Ps = KsPs;
    int tid = threadIdx.x;
    int id = blockIdx.x;
    int xcd = id & 7, j = id >> 3;
    int i0 = (xcd * 4 + (j & 3)) * 64;
    int hb = j >> 2;
    int h = hb & 15, b = hb >> 4;

    int wave = tid >> 6, lane = tid & 63;
    int llo = lane & 15, lhi = lane >> 4;

    // --- async K staging: rows j = i0-64 .. i0+127 from k_h[b][j][h*64..] ---
    {
        int srow = lane >> 3;
        int chunk = ((lane & 7) ^ (lane >> 3)) * 8;
        const _Float16* kb = k_h + (size_t)(b * NN) * DD + h * DHH + chunk;
#pragma unroll
        for (int q = 0; q < 6; ++q) {
            int p = wave * 6 + q;
            int jj = i0 - 64 + p * 8 + srow;   // may be OOR: mapped garbage, masked later
            __builtin_amdgcn_global_load_lds(AS1(kb + (ptrdiff_t)jj * DD), AS3(Ks + p * 512 + lane * 8), 16, 0, 0);
        }
    }

    // --- V^T staging: plain copy of 64 dh-rows x 192 tokens from vt_h ---
    {
        const _Float16* vb = vt_h + (size_t)((b * HH + h) * DHH) * NN + (i0 - 64);
        for (int u = tid; u < 1536; u += 256) {
            int d = u / 24, c = u % 24;
            f16x8 vv = *(const f16x8*)(vb + (ptrdiff_t)d * NN + c * 8);
            *(f16x8*)(Vt + d * VP + c * 8) = vv;
        }
    }

    // --- Q fragments straight from global ---
    int qrow = wave * 16 + llo;
    int qi = i0 + qrow;
    const _Float16* qp = q_h + (size_t)(b * NN + qi) * DD + h * DHH;
    f16x8 qf0 = *(const f16x8*)(qp + lhi * 8);
    f16x8 qf1 = *(const f16x8*)(qp + 32 + lhi * 8);
    __syncthreads();

    // --- S^T = K @ Q^T (swizzled Ks reads; row&7 == llo&7) ---
    float sc[12][4];
#pragma unroll
    for (int mt = 0; mt < 12; ++mt) {
        const _Float16* kr = Ks + (mt * 16 + llo) * 64;
        f16x8 kf0 = *(const f16x8*)(kr + ((lhi ^ (llo & 7)) * 8));
        f16x8 kf1 = *(const f16x8*)(kr + (((lhi + 4) ^ (llo & 7)) * 8));
        f32x4 a = {0.f, 0.f, 0.f, 0.f};
        a = __builtin_amdgcn_mfma_f32_16x16x32_f16(kf0, qf0, a, 0, 0, 0);
        a = __builtin_amdgcn_mfma_f32_16x16x32_f16(kf1, qf1, a, 0, 0, 0);
#pragma unroll
        for (int r = 0; r < 4; ++r) sc[mt][r] = a[r];
    }
    __syncthreads();   // all waves done reading Ks; its LDS is now P's

    // --- masked softmax over 192 slots of query qi ---
    float m = -1e30f;
#pragma unroll
    for (int mt = 0; mt < 12; ++mt)
#pragma unroll
        for (int r = 0; r < 4; ++r) {
            int sidx = mt * 16 + lhi * 4 + r;
            int jj = i0 - 64 + sidx;
            int dj = jj - qi;
            bool valid = (jj >= 0) && (jj < NN) && (dj <= 64) && (dj >= -64);
            float v = valid ? sc[mt][r] * SCALE : -1e30f;   // select: garbage never propagates
            sc[mt][r] = v;
            m = fmaxf(m, v);
        }
    m = fmaxf(m, __shfl_xor(m, 16, 64));
    m = fmaxf(m, __shfl_xor(m, 32, 64));
    float l = 0.f;
#pragma unroll
    for (int mt = 0; mt < 12; ++mt)
#pragma unroll
        for (int r = 0; r < 4; ++r) {
            float e = __expf(sc[mt][r] - m);
            sc[mt][r] = e;
            l += e;
        }
    l += __shfl_xor(l, 16, 64);
    l += __shfl_xor(l, 32, 64);
    float invl = 1.f / l;

    // --- write normalized P rows (overlays Ks; own rows -> wave-local wait) ---
#pragma unroll
    for (int mt = 0; mt < 12; ++mt) {
        f16x4 pv;
#pragma unroll
        for (int r = 0; r < 4; ++r) pv[r] = (_Float16)(sc[mt][r] * invl);
        *(f16x4*)(Ps + qrow * PP + mt * 16 + lhi * 4) = pv;
    }
    __asm__ volatile("s_waitcnt lgkmcnt(0)" ::: "memory");  // wave-local P write->read

    // --- O = P @ V ---
    f32x4 oacc[4] = {};
#pragma unroll
    for (int ks = 0; ks < 6; ++ks) {
        f16x8 pf = *(const f16x8*)(Ps + (wave * 16 + llo) * PP + ks * 32 + lhi * 8);
#pragma unroll
        for (int nt = 0; nt < 4; ++nt) {
            f16x8 vf = *(const f16x8*)(Vt + (nt * 16 + llo) * VP + ks * 32 + lhi * 8);
            oacc[nt] = __builtin_amdgcn_mfma_f32_16x16x32_f16(pf, vf, oacc[nt], 0, 0, 0);
        }
    }

    // --- epilogue: col=llo=dh, row=lhi*4+r=query ---
    _Float16* orow = outh + (size_t)(b * NN) * DD + h * DHH;
#pragma unroll
    for (int nt = 0; nt < 4; ++nt)
#pragma unroll
        for (int r = 0; r < 4; ++r) {
            int q = wave * 16 + lhi * 4 + r;
            int d = nt * 16 + llo;
            orow[(size_t)(i0 + q) * DD + d] = (_Float16)oacc[nt][r];
        }
}

// ---------------- launch ----------------
extern "C" void kernel_launch(void* const* d_in, const int* in_sizes, int n_in,
                              void* d_out, int out_size, void* d_ws, size_t ws_size,
                              hipStream_t stream) {
    const float* x    = (const float*)d_in[0];
    const float* Wqkv = (const float*)d_in[1];
    const float* bqkv = (const float*)d_in[2];
    const float* Wout = (const float*)d_in[3];
    const float* bout = (const float*)d_in[4];
    float* out = (float*)d_out;

    char* ws = (char*)d_ws;
    _Float16* x_h    = (_Float16*)(ws);                              //  8 MB [4096][1024]
    _Float16* Wqkv_t = (_Float16*)(ws + (size_t)8  * 1024 * 1024);   //  6 MB [3072][1024]
    _Float16* Wout_t = (_Float16*)(ws + (size_t)14 * 1024 * 1024);   //  2 MB [1024][1024]
    _Float16* q_h    = (_Float16*)(ws + (size_t)16 * 1024 * 1024);   //  8 MB [2][2048][1024]
    _Float16* k_h    = (_Float16*)(ws + (size_t)24 * 1024 * 1024);   //  8 MB [2][2048][1024]
    _Float16* vt_h   = (_Float16*)(ws + (size_t)32 * 1024 * 1024);   //  8 MB [2*16*64][2048]
    _Float16* attn_h = (_Float16*)(ws + (size_t)40 * 1024 * 1024);   //  8 MB [4096][1024]

    prep<<<6144, 256, 0, stream>>>(x, x_h, Wqkv, Wqkv_t, Wout, Wout_t);

    gemm_qkv<<<192, 512, 0, stream>>>(x_h, Wqkv_t, bqkv, q_h, k_h, vt_h);

    local_attn<<<1024, 256, 0, stream>>>(q_h, k_h, vt_h, attn_h);

    gemm_out<<<256, 256, 0, stream>>>(attn_h, Wout_t, bout, out);
}

// Round 9
// 150.852 us; speedup vs baseline: 1.7143x; 1.0042x over previous
//
#include <hip/hip_runtime.h>
#include <hip/hip_bf16.h>
#include <cstdint>
#include <cstddef>

// Problem constants (B=2, N=2048, D=1024, H=16, DH=64, window +-64)
#define BB 2
#define NN 2048
#define DD 1024
#define HH 16
#define DHH 64
#define SCALE 0.125f

typedef _Float16 f16x8 __attribute__((ext_vector_type(8)));
typedef _Float16 f16x4 __attribute__((ext_vector_type(4)));
typedef float f32x4 __attribute__((ext_vector_type(4)));

#define AS1(p) ((__attribute__((address_space(1))) void*)(p))
#define AS3(p) ((__attribute__((address_space(3))) void*)(p))

// ---------------- fused prep: x cast + both weight transposes, one launch ----------------
__global__ __launch_bounds__(256) void prep(const float* __restrict__ x, _Float16* __restrict__ x_h,
                                            const float* __restrict__ Wqkv, _Float16* __restrict__ Wqkv_t,
                                            const float* __restrict__ Wout, _Float16* __restrict__ Wout_t) {
    __shared__ float tile[32][33];
    int bx = blockIdx.x, tid = threadIdx.x;
    if (bx < 2048) {
        int i = bx * 2048 + tid * 8;
        f32x4 a = *(const f32x4*)(x + i);
        f32x4 b = *(const f32x4*)(x + i + 4);
        f16x8 o;
        o[0] = (_Float16)a[0]; o[1] = (_Float16)a[1]; o[2] = (_Float16)a[2]; o[3] = (_Float16)a[3];
        o[4] = (_Float16)b[0]; o[5] = (_Float16)b[1]; o[6] = (_Float16)b[2]; o[7] = (_Float16)b[3];
        *(f16x8*)(x_h + i) = o;
        return;
    }
    const float* in; _Float16* out; int C, tc, tr;
    if (bx < 5120) { int t = bx - 2048; C = 3 * DD; in = Wqkv; out = Wqkv_t; tc = t % 96; tr = t / 96; }
    else           { int t = bx - 5120; C = DD;     in = Wout; out = Wout_t; tc = t % 32; tr = t / 32; }
    int R = DD;
    int txx = tid & 31, ty = tid >> 5;
    int r0 = tr * 32, c0 = tc * 32;
#pragma unroll
    for (int i = 0; i < 32; i += 8)
        tile[ty + i][txx] = in[(size_t)(r0 + ty + i) * C + (c0 + txx)];
    __syncthreads();
#pragma unroll
    for (int i = 0; i < 32; i += 8)
        out[(size_t)(c0 + ty + i) * R + (r0 + txx)] = (_Float16)tile[txx][ty + i];
}

// ---------------- shared K-loop body (R6 family) — used by gemm_out only ----------------
template <bool SWAP, int MT>
__device__ __forceinline__ void gemm_kloop(const _Float16* __restrict__ gA,
                                           const _Float16* __restrict__ gB,
                                           _Float16* lA, _Float16* lB,
                                           const _Float16* As, const _Float16* Bs,
                                           int wm, int wn, int llo, int lhi, int K,
                                           f32x4 acc[][MT > 4 ? MT : 4]) {
    for (int k0 = 0; k0 < K; k0 += 64) {
        __syncthreads();
#pragma unroll
        for (int p = 0; p < MT; ++p)
            __builtin_amdgcn_global_load_lds(AS1(gA + (size_t)p * 8 * K + k0), AS3(lA + p * 512), 16, 0, 0);
#pragma unroll
        for (int p = 0; p < 4; ++p)
            __builtin_amdgcn_global_load_lds(AS1(gB + (size_t)p * 8 * K + k0), AS3(lB + p * 512), 16, 0, 0);
        __syncthreads();

#pragma unroll
        for (int ks = 0; ks < 2; ++ks) {
            f16x8 af[MT], bf[4];
            int swz = (((ks * 4 + lhi) ^ (llo & 7)) * 8);
#pragma unroll
            for (int mt = 0; mt < MT; ++mt)
                af[mt] = *(const f16x8*)(As + (wm + mt * 16 + llo) * 64 + swz);
#pragma unroll
            for (int nt = 0; nt < 4; ++nt)
                bf[nt] = *(const f16x8*)(Bs + (wn + nt * 16 + llo) * 64 + swz);
            if (SWAP) {
#pragma unroll
                for (int nt = 0; nt < 4; ++nt)
#pragma unroll
                    for (int mt = 0; mt < MT; ++mt)
                        acc[nt][mt] = __builtin_amdgcn_mfma_f32_16x16x32_f16(bf[nt], af[mt], acc[nt][mt], 0, 0, 0);
            } else {
#pragma unroll
                for (int mt = 0; mt < MT; ++mt)
#pragma unroll
                    for (int nt = 0; nt < 4; ++nt)
                        acc[mt][nt] = __builtin_amdgcn_mfma_f32_16x16x32_f16(af[mt], bf[nt], acc[mt][nt], 0, 0, 0);
            }
        }
    }
}

// ---------------- QKV GEMM v7: 256x192 tile, 256 blocks = exact CU fill, all-SWAP ----------------
// Grid 16M x 16N fills all 256 CUs (was 192/256 -> 25% idle). Per-block work x0.75.
// All blocks SWAP (C^T); region resolved per 8-col chunk in the epilogue:
//   q/k chunks: LDS-restaged coalesced f16x8 row-stores (stride-48 R, mod-6 rotate swizzle).
//   v chunks (cols 2048..3072): direct transposed scalar f16 stores into vt_h.
// K-loop = v6 2-phase schedule, ledger for 7 loads/K-tile (A0:2, B:3, A1:2):
//   prologue vmcnt(2); P1-end vmcnt(5) [A1(t)]; P2-end vmcnt(2) [A0',B'(t+1)]; peel 2->0.
// Per wave: output 128 tok x 48 feat (wm=(wave>>2)*128, wn=(wave&3)*48), acc[3][8] f32x4.
// LDS: As 2x[256][64]=64KB, Bs 2x[192][64]=48KB -> 112 KB, 1 block/CU.
__global__ __launch_bounds__(512, 2) void gemm_qkv(const _Float16* __restrict__ A,
                                                   const _Float16* __restrict__ Bt,
                                                   const float* __restrict__ bias,
                                                   _Float16* __restrict__ q_h,
                                                   _Float16* __restrict__ k_h,
                                                   _Float16* __restrict__ vt_h) {
    __shared__ __align__(16) _Float16 As[2 * 16384];   // 64 KiB: 2 x [256][64]
    __shared__ __align__(16) _Float16 Bs[2 * 12288];   // 48 KiB: 2 x [192][64]
    int id = blockIdx.x;
    int xcd = id & 7, jj = id >> 3;                    // 32 tiles per XCD chunk
    int mtile = (xcd >> 1) * 4 + (jj >> 3);            // 16 M-tiles = 4 groups of 4
    int ntile = (xcd & 1) * 8 + (jj & 7);              // 16 N-tiles = 2 groups of 8
    int bm = mtile * 256, bn = ntile * 192;

    int tid = threadIdx.x;
    int wave = tid >> 6, lane = tid & 63;
    int llo = lane & 15, lhi = lane >> 4;
    int wm = (wave >> 2) * 128, wn = (wave & 3) * 48;  // per-wave 128x48 output tile
    int l8 = lane >> 3;
    int gchunk = ((lane & 7) ^ l8) * 8;                // inverse-swizzled source chunk

    int rAu = wm + (wave & 3) * 16;                    // A staging rows (as v6)
    const _Float16* gA = A + (size_t)(bm + rAu + l8) * DD + gchunk;
    _Float16* lA = As + rAu * 64 + lane * 8;
    const _Float16* gB = Bt + (size_t)(bn + wave * 8 + l8) * DD + gchunk;   // B: wave w covers rows g*64+w*8..+8
    _Float16* lB = Bs + wave * 512 + lane * 8;

#define STA(H, C, T, U) __builtin_amdgcn_global_load_lds( \
        AS1(gA + (size_t)((H) * 64 + (C) * 8) * DD + (T) * 64), \
        AS3(lA + (U) * 16384 + ((H) * 64 + (C) * 8) * 64), 16, 0, 0)
#define STB(G, T, U) __builtin_amdgcn_global_load_lds( \
        AS1(gB + (size_t)((G) * 64) * DD + (T) * 64), \
        AS3(lB + (U) * 12288 + (G) * 4096), 16, 0, 0)
#define RDA(MT, KS, U) (*(const f16x8*)(As + (U) * 16384 + (wm + (MT) * 16 + llo) * 64 + ((((KS) * 4 + lhi) ^ (llo & 7)) * 8)))
#define RDB(NT, KS, U) (*(const f16x8*)(Bs + (U) * 12288 + (wn + (NT) * 16 + llo) * 64 + ((((KS) * 4 + lhi) ^ (llo & 7)) * 8)))
#define MM(MT, NT, KS) \
        acc[NT][MT] = __builtin_amdgcn_mfma_f32_16x16x32_f16(bf[NT][KS], af[(MT) & 3][KS], acc[NT][MT], 0, 0, 0)

    f32x4 acc[3][8] = {};        // [nt][mt] = C^T fragments
    f16x8 af[4][2], bf[3][2];

    // prologue: K-tile 0 into buf 0, FIFO order = consumption order: A0(2), B(3), A1(2)
    STA(0, 0, 0, 0); STA(0, 1, 0, 0);
    STB(0, 0, 0); STB(1, 0, 0); STB(2, 0, 0);
    STA(1, 0, 0, 0); STA(1, 1, 0, 0);
    asm volatile("s_waitcnt vmcnt(2)" ::: "memory");   // A0,B landed; A1 in flight
    __builtin_amdgcn_s_barrier();

#pragma unroll 1
    for (int t = 0; t < 15; ++t) {
        int u = t & 1, nu = u ^ 1;
        // ---- P1: read A0 (mt0-3, 8 b128) + B (nt0-2, 6 b128); stage A0'(2)+B'(3); 24 MFMA
#pragma unroll
        for (int mt = 0; mt < 4; ++mt) { af[mt][0] = RDA(mt, 0, u); af[mt][1] = RDA(mt, 1, u); }
#pragma unroll
        for (int nt = 0; nt < 3; ++nt) { bf[nt][0] = RDB(nt, 0, u); bf[nt][1] = RDB(nt, 1, u); }
        STA(0, 0, t + 1, nu); STA(0, 1, t + 1, nu);
        STB(0, t + 1, nu); STB(1, t + 1, nu); STB(2, t + 1, nu);
        __builtin_amdgcn_s_barrier();
        asm volatile("s_waitcnt lgkmcnt(0)" ::: "memory");
        __builtin_amdgcn_s_setprio(1);
#pragma unroll
        for (int ks = 0; ks < 2; ++ks)
#pragma unroll
            for (int mt = 0; mt < 4; ++mt) { MM(mt, 0, ks); MM(mt, 1, ks); MM(mt, 2, ks); }
        __builtin_amdgcn_s_setprio(0);
        asm volatile("s_waitcnt vmcnt(5)" ::: "memory");   // A1(t) landed (issued P2(t-1))
        __builtin_amdgcn_s_barrier();
        // ---- P2: read A1 (mt4-7); stage A1'(2); 24 MFMA
#pragma unroll
        for (int mt = 0; mt < 4; ++mt) { af[mt][0] = RDA(mt + 4, 0, u); af[mt][1] = RDA(mt + 4, 1, u); }
        STA(1, 0, t + 1, nu); STA(1, 1, t + 1, nu);
        __builtin_amdgcn_s_barrier();
        asm volatile("s_waitcnt lgkmcnt(0)" ::: "memory");
        __builtin_amdgcn_s_setprio(1);
#pragma unroll
        for (int ks = 0; ks < 2; ++ks)
#pragma unroll
            for (int mt = 4; mt < 8; ++mt) { MM(mt, 0, ks); MM(mt, 1, ks); MM(mt, 2, ks); }
        __builtin_amdgcn_s_setprio(0);
        asm volatile("s_waitcnt vmcnt(2)" ::: "memory");   // A0',B'(t+1) landed
        __builtin_amdgcn_s_barrier();
    }

    // ---- peeled K-tile 15 (buf 1): drain 2 -> 0
    {
#pragma unroll
        for (int mt = 0; mt < 4; ++mt) { af[mt][0] = RDA(mt, 0, 1); af[mt][1] = RDA(mt, 1, 1); }
#pragma unroll
        for (int nt = 0; nt < 3; ++nt) { bf[nt][0] = RDB(nt, 0, 1); bf[nt][1] = RDB(nt, 1, 1); }
        asm volatile("s_waitcnt lgkmcnt(0)" ::: "memory");
        __builtin_amdgcn_s_setprio(1);
#pragma unroll
        for (int ks = 0; ks < 2; ++ks)
#pragma unroll
            for (int mt = 0; mt < 4; ++mt) { MM(mt, 0, ks); MM(mt, 1, ks); MM(mt, 2, ks); }
        __builtin_amdgcn_s_setprio(0);
        asm volatile("s_waitcnt vmcnt(0)" ::: "memory");   // A1(15) landed
        __builtin_amdgcn_s_barrier();
#pragma unroll
        for (int mt = 0; mt < 4; ++mt) { af[mt][0] = RDA(mt + 4, 0, 1); af[mt][1] = RDA(mt + 4, 1, 1); }
        asm volatile("s_waitcnt lgkmcnt(0)" ::: "memory");
        __builtin_amdgcn_s_setprio(1);
#pragma unroll
        for (int ks = 0; ks < 2; ++ks)
#pragma unroll
            for (int mt = 4; mt < 8; ++mt) { MM(mt, 0, ks); MM(mt, 1, ks); MM(mt, 2, ks); }
        __builtin_amdgcn_s_setprio(0);
    }

    // ---- epilogue: per-chunk region; q/k via LDS restage + f16x8 rows; v direct transposed ----
    __builtin_amdgcn_s_barrier();      // all waves done with K-loop LDS reads; As/Bs now dead
    _Float16* R = (wave < 4) ? (As + wave * 6144) : (Bs + (wave - 4) * 6144);  // 12 KB/wave
    int bq = bm >> 11;                 // batch (256-tile never crosses n=2048)
    int nb = (bm & 2047) + wm;         // wave's first token within batch
    int cwb = bn + wn;                 // wave's absolute first output col (0..3072)

    // pass 1a: restage [tok 128][feat 48], slot = (chunk + t) % 6 (rotate; chunk 0..5)
#pragma unroll
    for (int nt = 0; nt < 3; ++nt) {
        int fb = nt * 16 + lhi * 4;                    // 0..44
        f32x4 b4 = *(const f32x4*)(bias + cwb + fb);
        int chunk = fb >> 3, off = fb & 7;             // off = 0 or 4
#pragma unroll
        for (int mt = 0; mt < 8; ++mt) {
            int t = mt * 16 + llo;
            f16x4 v4;
#pragma unroll
            for (int r = 0; r < 4; ++r) v4[r] = (_Float16)(acc[nt][mt][r] + b4[r]);
            *(f16x4*)(R + t * 48 + ((chunk + t) % 6) * 8 + off) = v4;
        }
    }
    asm volatile("s_waitcnt lgkmcnt(0)" ::: "memory");   // wave-local write->read
    // pass 1b: coalesced f16x8 row stores for q/k chunks
#pragma unroll
    for (int it = 0; it < 16; ++it) {
        int t = it * 8 + l8;
        int c = lane & 7;
        if (c < 6) {
            int col = cwb + c * 8;
            int rg = col >> 10;
            if (rg < 2) {
                f16x8 v = *(const f16x8*)(R + t * 48 + ((c + t) % 6) * 8);
                _Float16* dst = rg ? k_h : q_h;
                *(f16x8*)(dst + (size_t)(bq * NN + nb + t) * DD + (col & 1023)) = v;
            }
        }
    }
    // pass 2: v chunks direct transposed scalar stores
#pragma unroll
    for (int nt = 0; nt < 3; ++nt) {
        int colbase = cwb + nt * 16;
        if ((colbase >> 10) == 2) {
            int fb = nt * 16 + lhi * 4;
            f32x4 b4 = *(const f32x4*)(bias + cwb + fb);
#pragma unroll
            for (int r = 0; r < 4; ++r) {
                int c1023 = (colbase + lhi * 4 + r) & 1023;
                int h = c1023 >> 6, dh = c1023 & 63;
                _Float16* vb = vt_h + ((size_t)((bq * HH + h) * DHH + dh)) * NN;
#pragma unroll
                for (int mt = 0; mt < 8; ++mt) {
                    int n = nb + mt * 16 + llo;
                    vb[n] = (_Float16)(acc[nt][mt][r] + b4[r]);
                }
            }
        }
    }
#undef STA
#undef STB
#undef RDA
#undef RDB
#undef MM
}

// ---------------- out-proj GEMM v2: 128x128 tile (R0-verified kloop<true,4> path) ----------------
__global__ __launch_bounds__(256) void gemm_out(const _Float16* __restrict__ A,
                                                const _Float16* __restrict__ Bt,
                                                const float* __restrict__ bias,
                                                float* __restrict__ Cf) {
    const int K = DD, N = DD;
    __shared__ __align__(16) _Float16 As[128 * 64];
    __shared__ __align__(16) _Float16 Bs[128 * 64];
    int id = blockIdx.x;
    int xcd = id & 7, j = id >> 3;            // 32 tiles per XCD chunk
    int bm = (xcd * 4 + (j >> 3)) * 128;      // 32 m-tiles = 8 xcd x 4
    int bn = (j & 7) * 128;                   // 8 n-tiles
    int tid = threadIdx.x;
    int wave = tid >> 6, lane = tid & 63;
    int wm = (wave >> 1) * 64, wn = (wave & 1) * 64;
    int lhi = lane >> 4, llo = lane & 15;

    f32x4 acc[4][4] = {};   // [nt][mt]

    int srow = wave * 32 + (lane >> 3);
    int scol = ((lane & 7) ^ (lane >> 3)) * 8;
    const _Float16* gA = A + (size_t)(bm + srow) * K + scol;
    const _Float16* gB = Bt + (size_t)(bn + srow) * K + scol;
    _Float16* lA = As + wave * 2048 + lane * 8;
    _Float16* lB = Bs + wave * 2048 + lane * 8;

    gemm_kloop<true, 4>(gA, gB, lA, lB, As, Bs, wm, wn, llo, lhi, K, acc);

#pragma unroll
    for (int nt = 0; nt < 4; ++nt) {
        int cbase = bn + wn + nt * 16 + lhi * 4;
        f32x4 b4 = *(const f32x4*)(bias + cbase);
#pragma unroll
        for (int mt = 0; mt < 4; ++mt) {
            int t = bm + wm + mt * 16 + llo;
            f32x4 v4;
#pragma unroll
            for (int r = 0; r < 4; ++r) v4[r] = acc[nt][mt][r] + b4[r];
            *(f32x4*)(Cf + (size_t)t * N + cbase) = v4;
        }
    }
}

// ---------------- windowed attention (R0-proven: QBLK=64, Ks/P LDS overlay, 3 blocks/CU) ----------------
#define KP 64
#define PP 200   // P stride: 400B (16B-aligned), rows 4 banks apart
#define VP 200
__global__ __launch_bounds__(256) void local_attn(const _Float16* __restrict__ q_h,
                                                  const _Float16* __restrict__ k_h,
                                                  const _Float16* __restrict__ vt_h,
                                                  _Float16* __restrict__ outh) {
    __shared__ __align__(16) _Float16 KsPs[64 * PP];  // 25600 B: Ks[192*64] overlaid by P[64*PP]
    __shared__ __align__(16) _Float16 Vt[64 * VP];    // 25600 B
    _Float16* Ks = KsPs;
    _Float16* Ps = KsPs;
    int tid = threadIdx.x;
    int id = blockIdx.x;
    int xcd = id & 7, j = id >> 3;
    int i0 = (xcd * 4 + (j & 3)) * 64;
    int hb = j >> 2;
    int h = hb & 15, b = hb >> 4;

    int wave = tid >> 6, lane = tid & 63;
    int llo = lane & 15, lhi = lane >> 4;

    // --- async K staging: rows j = i0-64 .. i0+127 from k_h[b][j][h*64..] ---
    {
        int srow = lane >> 3;
        int chunk = ((lane & 7) ^ (lane >> 3)) * 8;
        const _Float16* kb = k_h + (size_t)(b * NN) * DD + h * DHH + chunk;
#pragma unroll
        for (int q = 0; q < 6; ++q) {
            int p = wave * 6 + q;
            int jj = i0 - 64 + p * 8 + srow;   // may be OOR: mapped garbage, masked later
            __builtin_amdgcn_global_load_lds(AS1(kb + (ptrdiff_t)jj * DD), AS3(Ks + p * 512 + lane * 8), 16, 0, 0);
        }
    }

    // --- V^T staging: plain copy of 64 dh-rows x 192 tokens from vt_h ---
    {
        const _Float16* vb = vt_h + (size_t)((b * HH + h) * DHH) * NN + (i0 - 64);
        for (int u = tid; u < 1536; u += 256) {
            int d = u / 24, c = u % 24;
            f16x8 vv = *(const f16x8*)(vb + (ptrdiff_t)d * NN + c * 8);
            *(f16x8*)(Vt + d * VP + c * 8) = vv;
        }
    }

    // --- Q fragments straight from global ---
    int qrow = wave * 16 + llo;
    int qi = i0 + qrow;
    const _Float16* qp = q_h + (size_t)(b * NN + qi) * DD + h * DHH;
    f16x8 qf0 = *(const f16x8*)(qp + lhi * 8);
    f16x8 qf1 = *(const f16x8*)(qp + 32 + lhi * 8);
    __syncthreads();

    // --- S^T = K @ Q^T (swizzled Ks reads; row&7 == llo&7) ---
    float sc[12][4];
#pragma unroll
    for (int mt = 0; mt < 12; ++mt) {
        const _Float16* kr = Ks + (mt * 16 + llo) * 64;
        f16x8 kf0 = *(const f16x8*)(kr + ((lhi ^ (llo & 7)) * 8));
        f16x8 kf1 = *(const f16x8*)(kr + (((lhi + 4) ^ (llo & 7)) * 8));
        f32x4 a = {0.f, 0.f, 0.f, 0.f};
        a = __builtin_amdgcn_mfma_f32_16x16x32_f16(kf0, qf0, a, 0, 0, 0);
        a = __builtin_amdgcn_mfma_f32_16x16x32_f16(kf1, qf1, a, 0, 0, 0);
#pragma unroll
        for (int r = 0; r < 4; ++r) sc[mt][r] = a[r];
    }
    __syncthreads();   // all waves done reading Ks; its LDS is now P's

    // --- masked softmax over 192 slots of query qi ---
    float m = -1e30f;
#pragma unroll
    for (int mt = 0; mt < 12; ++mt)
#pragma unroll
        for (int r = 0; r < 4; ++r) {
            int sidx = mt * 16 + lhi * 4 + r;
            int jj = i0 - 64 + sidx;
            int dj = jj - qi;
            bool valid = (jj >= 0) && (jj < NN) && (dj <= 64) && (dj >= -64);
            float v = valid ? sc[mt][r] * SCALE : -1e30f;   // select: garbage never propagates
            sc[mt][r] = v;
            m = fmaxf(m, v);
        }
    m = fmaxf(m, __shfl_xor(m, 16, 64));
    m = fmaxf(m, __shfl_xor(m, 32, 64));
    float l = 0.f;
#pragma unroll
    for (int mt = 0; mt < 12; ++mt)
#pragma unroll
        for (int r = 0; r < 4; ++r) {
            float e = __expf(sc[mt][r] - m);
            sc[mt][r] = e;
            l += e;
        }
    l += __shfl_xor(l, 16, 64);
    l += __shfl_xor(l, 32, 64);
    float invl = 1.f / l;

    // --- write normalized P rows (overlays Ks; own rows -> wave-local wait) ---
#pragma unroll
    for (int mt = 0; mt < 12; ++mt) {
        f16x4 pv;
#pragma unroll
        for (int r = 0; r < 4; ++r) pv[r] = (_Float16)(sc[mt][r] * invl);
        *(f16x4*)(Ps + qrow * PP + mt * 16 + lhi * 4) = pv;
    }
    __asm__ volatile("s_waitcnt lgkmcnt(0)" ::: "memory");  // wave-local P write->read

    // --- O = P @ V ---
    f32x4 oacc[4] = {};
#pragma unroll
    for (int ks = 0; ks < 6; ++ks) {
        f16x8 pf = *(const f16x8*)(Ps + (wave * 16 + llo) * PP + ks * 32 + lhi * 8);
#pragma unroll
        for (int nt = 0; nt < 4; ++nt) {
            f16x8 vf = *(const f16x8*)(Vt + (nt * 16 + llo) * VP + ks * 32 + lhi * 8);
            oacc[nt] = __builtin_amdgcn_mfma_f32_16x16x32_f16(pf, vf, oacc[nt], 0, 0, 0);
        }
    }

    // --- epilogue: col=llo=dh, row=lhi*4+r=query ---
    _Float16* orow = outh + (size_t)(b * NN) * DD + h * DHH;
#pragma unroll
    for (int nt = 0; nt < 4; ++nt)
#pragma unroll
        for (int r = 0; r < 4; ++r) {
            int q = wave * 16 + lhi * 4 + r;
            int d = nt * 16 + llo;
            orow[(size_t)(i0 + q) * DD + d] = (_Float16)oacc[nt][r];
        }
}

// ---------------- launch ----------------
extern "C" void kernel_launch(void* const* d_in, const int* in_sizes, int n_in,
                              void* d_out, int out_size, void* d_ws, size_t ws_size,
                              hipStream_t stream) {
    const float* x    = (const float*)d_in[0];
    const float* Wqkv = (const float*)d_in[1];
    const float* bqkv = (const float*)d_in[2];
    const float* Wout = (const float*)d_in[3];
    const float* bout = (const float*)d_in[4];
    float* out = (float*)d_out;

    char* ws = (char*)d_ws;
    _Float16* x_h    = (_Float16*)(ws);                              //  8 MB [4096][1024]
    _Float16* Wqkv_t = (_Float16*)(ws + (size_t)8  * 1024 * 1024);   //  6 MB [3072][1024]
    _Float16* Wout_t = (_Float16*)(ws + (size_t)14 * 1024 * 1024);   //  2 MB [1024][1024]
    _Float16* q_h    = (_Float16*)(ws + (size_t)16 * 1024 * 1024);   //  8 MB [2][2048][1024]
    _Float16* k_h    = (_Float16*)(ws + (size_t)24 * 1024 * 1024);   //  8 MB [2][2048][1024]
    _Float16* vt_h   = (_Float16*)(ws + (size_t)32 * 1024 * 1024);   //  8 MB [2*16*64][2048]
    _Float16* attn_h = (_Float16*)(ws + (size_t)40 * 1024 * 1024);   //  8 MB [4096][1024]

    prep<<<6144, 256, 0, stream>>>(x, x_h, Wqkv, Wqkv_t, Wout, Wout_t);

    gemm_qkv<<<256, 512, 0, stream>>>(x_h, Wqkv_t, bqkv, q_h, k_h, vt_h);

    local_attn<<<1024, 256, 0, stream>>>(q_h, k_h, vt_h, attn_h);

    gemm_out<<<256, 256, 0, stream>>>(attn_h, Wout_t, bout, out);
}

// Round 10
// 145.380 us; speedup vs baseline: 1.7788x; 1.0376x over previous
//
#include <hip/hip_runtime.h>
#include <hip/hip_bf16.h>
#include <cstdint>
#include <cstddef>

// Problem constants (B=2, N=2048, D=1024, H=16, DH=64, window +-64)
#define BB 2
#define NN 2048
#define DD 1024
#define HH 16
#define DHH 64
#define SCALE 0.125f

typedef _Float16 f16x8 __attribute__((ext_vector_type(8)));
typedef _Float16 f16x4 __attribute__((ext_vector_type(4)));
typedef float f32x4 __attribute__((ext_vector_type(4)));

#define AS1(p) ((__attribute__((address_space(1))) void*)(p))
#define AS3(p) ((__attribute__((address_space(3))) void*)(p))

// ---------------- fused prep: x cast + both weight transposes, one launch ----------------
__global__ __launch_bounds__(256) void prep(const float* __restrict__ x, _Float16* __restrict__ x_h,
                                            const float* __restrict__ Wqkv, _Float16* __restrict__ Wqkv_t,
                                            const float* __restrict__ Wout, _Float16* __restrict__ Wout_t) {
    __shared__ float tile[32][33];
    int bx = blockIdx.x, tid = threadIdx.x;
    if (bx < 2048) {
        int i = bx * 2048 + tid * 8;
        f32x4 a = *(const f32x4*)(x + i);
        f32x4 b = *(const f32x4*)(x + i + 4);
        f16x8 o;
        o[0] = (_Float16)a[0]; o[1] = (_Float16)a[1]; o[2] = (_Float16)a[2]; o[3] = (_Float16)a[3];
        o[4] = (_Float16)b[0]; o[5] = (_Float16)b[1]; o[6] = (_Float16)b[2]; o[7] = (_Float16)b[3];
        *(f16x8*)(x_h + i) = o;
        return;
    }
    const float* in; _Float16* out; int C, tc, tr;
    if (bx < 5120) { int t = bx - 2048; C = 3 * DD; in = Wqkv; out = Wqkv_t; tc = t % 96; tr = t / 96; }
    else           { int t = bx - 5120; C = DD;     in = Wout; out = Wout_t; tc = t % 32; tr = t / 32; }
    int R = DD;
    int txx = tid & 31, ty = tid >> 5;
    int r0 = tr * 32, c0 = tc * 32;
#pragma unroll
    for (int i = 0; i < 32; i += 8)
        tile[ty + i][txx] = in[(size_t)(r0 + ty + i) * C + (c0 + txx)];
    __syncthreads();
#pragma unroll
    for (int i = 0; i < 32; i += 8)
        out[(size_t)(c0 + ty + i) * R + (r0 + txx)] = (_Float16)tile[txx][ty + i];
}

// ---------------- shared K-loop body (R6 family) — used by gemm_out only ----------------
template <bool SWAP, int MT>
__device__ __forceinline__ void gemm_kloop(const _Float16* __restrict__ gA,
                                           const _Float16* __restrict__ gB,
                                           _Float16* lA, _Float16* lB,
                                           const _Float16* As, const _Float16* Bs,
                                           int wm, int wn, int llo, int lhi, int K,
                                           f32x4 acc[][MT > 4 ? MT : 4]) {
    for (int k0 = 0; k0 < K; k0 += 64) {
        __syncthreads();
#pragma unroll
        for (int p = 0; p < MT; ++p)
            __builtin_amdgcn_global_load_lds(AS1(gA + (size_t)p * 8 * K + k0), AS3(lA + p * 512), 16, 0, 0);
#pragma unroll
        for (int p = 0; p < 4; ++p)
            __builtin_amdgcn_global_load_lds(AS1(gB + (size_t)p * 8 * K + k0), AS3(lB + p * 512), 16, 0, 0);
        __syncthreads();

#pragma unroll
        for (int ks = 0; ks < 2; ++ks) {
            f16x8 af[MT], bf[4];
            int swz = (((ks * 4 + lhi) ^ (llo & 7)) * 8);
#pragma unroll
            for (int mt = 0; mt < MT; ++mt)
                af[mt] = *(const f16x8*)(As + (wm + mt * 16 + llo) * 64 + swz);
#pragma unroll
            for (int nt = 0; nt < 4; ++nt)
                bf[nt] = *(const f16x8*)(Bs + (wn + nt * 16 + llo) * 64 + swz);
            if (SWAP) {
#pragma unroll
                for (int nt = 0; nt < 4; ++nt)
#pragma unroll
                    for (int mt = 0; mt < MT; ++mt)
                        acc[nt][mt] = __builtin_amdgcn_mfma_f32_16x16x32_f16(bf[nt], af[mt], acc[nt][mt], 0, 0, 0);
            } else {
#pragma unroll
                for (int mt = 0; mt < MT; ++mt)
#pragma unroll
                    for (int nt = 0; nt < 4; ++nt)
                        acc[mt][nt] = __builtin_amdgcn_mfma_f32_16x16x32_f16(af[mt], bf[nt], acc[mt][nt], 0, 0, 0);
            }
        }
    }
}

// ---------------- QKV GEMM v7 (R9-verified): 256x192 tile, 256 blocks = exact CU fill, all-SWAP ----------------
__global__ __launch_bounds__(512, 2) void gemm_qkv(const _Float16* __restrict__ A,
                                                   const _Float16* __restrict__ Bt,
                                                   const float* __restrict__ bias,
                                                   _Float16* __restrict__ q_h,
                                                   _Float16* __restrict__ k_h,
                                                   _Float16* __restrict__ vt_h) {
    __shared__ __align__(16) _Float16 As[2 * 16384];   // 64 KiB: 2 x [256][64]
    __shared__ __align__(16) _Float16 Bs[2 * 12288];   // 48 KiB: 2 x [192][64]
    int id = blockIdx.x;
    int xcd = id & 7, jj = id >> 3;                    // 32 tiles per XCD chunk
    int mtile = (xcd >> 1) * 4 + (jj >> 3);            // 16 M-tiles = 4 groups of 4
    int ntile = (xcd & 1) * 8 + (jj & 7);              // 16 N-tiles = 2 groups of 8
    int bm = mtile * 256, bn = ntile * 192;

    int tid = threadIdx.x;
    int wave = tid >> 6, lane = tid & 63;
    int llo = lane & 15, lhi = lane >> 4;
    int wm = (wave >> 2) * 128, wn = (wave & 3) * 48;  // per-wave 128x48 output tile
    int l8 = lane >> 3;
    int gchunk = ((lane & 7) ^ l8) * 8;                // inverse-swizzled source chunk

    int rAu = wm + (wave & 3) * 16;                    // A staging rows (as v6)
    const _Float16* gA = A + (size_t)(bm + rAu + l8) * DD + gchunk;
    _Float16* lA = As + rAu * 64 + lane * 8;
    const _Float16* gB = Bt + (size_t)(bn + wave * 8 + l8) * DD + gchunk;   // B: wave w covers rows g*64+w*8..+8
    _Float16* lB = Bs + wave * 512 + lane * 8;

#define STA(H, C, T, U) __builtin_amdgcn_global_load_lds( \
        AS1(gA + (size_t)((H) * 64 + (C) * 8) * DD + (T) * 64), \
        AS3(lA + (U) * 16384 + ((H) * 64 + (C) * 8) * 64), 16, 0, 0)
#define STB(G, T, U) __builtin_amdgcn_global_load_lds( \
        AS1(gB + (size_t)((G) * 64) * DD + (T) * 64), \
        AS3(lB + (U) * 12288 + (G) * 4096), 16, 0, 0)
#define RDA(MT, KS, U) (*(const f16x8*)(As + (U) * 16384 + (wm + (MT) * 16 + llo) * 64 + ((((KS) * 4 + lhi) ^ (llo & 7)) * 8)))
#define RDB(NT, KS, U) (*(const f16x8*)(Bs + (U) * 12288 + (wn + (NT) * 16 + llo) * 64 + ((((KS) * 4 + lhi) ^ (llo & 7)) * 8)))
#define MM(MT, NT, KS) \
        acc[NT][MT] = __builtin_amdgcn_mfma_f32_16x16x32_f16(bf[NT][KS], af[(MT) & 3][KS], acc[NT][MT], 0, 0, 0)

    f32x4 acc[3][8] = {};        // [nt][mt] = C^T fragments
    f16x8 af[4][2], bf[3][2];

    // prologue: K-tile 0 into buf 0, FIFO order = consumption order: A0(2), B(3), A1(2)
    STA(0, 0, 0, 0); STA(0, 1, 0, 0);
    STB(0, 0, 0); STB(1, 0, 0); STB(2, 0, 0);
    STA(1, 0, 0, 0); STA(1, 1, 0, 0);
    asm volatile("s_waitcnt vmcnt(2)" ::: "memory");   // A0,B landed; A1 in flight
    __builtin_amdgcn_s_barrier();

#pragma unroll 1
    for (int t = 0; t < 15; ++t) {
        int u = t & 1, nu = u ^ 1;
        // ---- P1: read A0 (mt0-3) + B (nt0-2); stage A0'(2)+B'(3); 24 MFMA
#pragma unroll
        for (int mt = 0; mt < 4; ++mt) { af[mt][0] = RDA(mt, 0, u); af[mt][1] = RDA(mt, 1, u); }
#pragma unroll
        for (int nt = 0; nt < 3; ++nt) { bf[nt][0] = RDB(nt, 0, u); bf[nt][1] = RDB(nt, 1, u); }
        STA(0, 0, t + 1, nu); STA(0, 1, t + 1, nu);
        STB(0, t + 1, nu); STB(1, t + 1, nu); STB(2, t + 1, nu);
        __builtin_amdgcn_s_barrier();
        asm volatile("s_waitcnt lgkmcnt(0)" ::: "memory");
        __builtin_amdgcn_s_setprio(1);
#pragma unroll
        for (int ks = 0; ks < 2; ++ks)
#pragma unroll
            for (int mt = 0; mt < 4; ++mt) { MM(mt, 0, ks); MM(mt, 1, ks); MM(mt, 2, ks); }
        __builtin_amdgcn_s_setprio(0);
        asm volatile("s_waitcnt vmcnt(5)" ::: "memory");   // A1(t) landed (issued P2(t-1))
        __builtin_amdgcn_s_barrier();
        // ---- P2: read A1 (mt4-7); stage A1'(2); 24 MFMA
#pragma unroll
        for (int mt = 0; mt < 4; ++mt) { af[mt][0] = RDA(mt + 4, 0, u); af[mt][1] = RDA(mt + 4, 1, u); }
        STA(1, 0, t + 1, nu); STA(1, 1, t + 1, nu);
        __builtin_amdgcn_s_barrier();
        asm volatile("s_waitcnt lgkmcnt(0)" ::: "memory");
        __builtin_amdgcn_s_setprio(1);
#pragma unroll
        for (int ks = 0; ks < 2; ++ks)
#pragma unroll
            for (int mt = 4; mt < 8; ++mt) { MM(mt, 0, ks); MM(mt, 1, ks); MM(mt, 2, ks); }
        __builtin_amdgcn_s_setprio(0);
        asm volatile("s_waitcnt vmcnt(2)" ::: "memory");   // A0',B'(t+1) landed
        __builtin_amdgcn_s_barrier();
    }

    // ---- peeled K-tile 15 (buf 1): drain 2 -> 0
    {
#pragma unroll
        for (int mt = 0; mt < 4; ++mt) { af[mt][0] = RDA(mt, 0, 1); af[mt][1] = RDA(mt, 1, 1); }
#pragma unroll
        for (int nt = 0; nt < 3; ++nt) { bf[nt][0] = RDB(nt, 0, 1); bf[nt][1] = RDB(nt, 1, 1); }
        asm volatile("s_waitcnt lgkmcnt(0)" ::: "memory");
        __builtin_amdgcn_s_setprio(1);
#pragma unroll
        for (int ks = 0; ks < 2; ++ks)
#pragma unroll
            for (int mt = 0; mt < 4; ++mt) { MM(mt, 0, ks); MM(mt, 1, ks); MM(mt, 2, ks); }
        __builtin_amdgcn_s_setprio(0);
        asm volatile("s_waitcnt vmcnt(0)" ::: "memory");   // A1(15) landed
        __builtin_amdgcn_s_barrier();
#pragma unroll
        for (int mt = 0; mt < 4; ++mt) { af[mt][0] = RDA(mt + 4, 0, 1); af[mt][1] = RDA(mt + 4, 1, 1); }
        asm volatile("s_waitcnt lgkmcnt(0)" ::: "memory");
        __builtin_amdgcn_s_setprio(1);
#pragma unroll
        for (int ks = 0; ks < 2; ++ks)
#pragma unroll
            for (int mt = 4; mt < 8; ++mt) { MM(mt, 0, ks); MM(mt, 1, ks); MM(mt, 2, ks); }
        __builtin_amdgcn_s_setprio(0);
    }

    // ---- epilogue: per-chunk region; q/k via LDS restage + f16x8 rows; v direct transposed ----
    __builtin_amdgcn_s_barrier();      // all waves done with K-loop LDS reads; As/Bs now dead
    _Float16* R = (wave < 4) ? (As + wave * 6144) : (Bs + (wave - 4) * 6144);  // 12 KB/wave
    int bq = bm >> 11;                 // batch (256-tile never crosses n=2048)
    int nb = (bm & 2047) + wm;         // wave's first token within batch
    int cwb = bn + wn;                 // wave's absolute first output col (0..3072)

    // pass 1a: restage [tok 128][feat 48], slot = (chunk + t) % 6 (rotate; chunk 0..5)
#pragma unroll
    for (int nt = 0; nt < 3; ++nt) {
        int fb = nt * 16 + lhi * 4;                    // 0..44
        f32x4 b4 = *(const f32x4*)(bias + cwb + fb);
        int chunk = fb >> 3, off = fb & 7;             // off = 0 or 4
#pragma unroll
        for (int mt = 0; mt < 8; ++mt) {
            int t = mt * 16 + llo;
            f16x4 v4;
#pragma unroll
            for (int r = 0; r < 4; ++r) v4[r] = (_Float16)(acc[nt][mt][r] + b4[r]);
            *(f16x4*)(R + t * 48 + ((chunk + t) % 6) * 8 + off) = v4;
        }
    }
    asm volatile("s_waitcnt lgkmcnt(0)" ::: "memory");   // wave-local write->read
    // pass 1b: coalesced f16x8 row stores for q/k chunks
#pragma unroll
    for (int it = 0; it < 16; ++it) {
        int t = it * 8 + l8;
        int c = lane & 7;
        if (c < 6) {
            int col = cwb + c * 8;
            int rg = col >> 10;
            if (rg < 2) {
                f16x8 v = *(const f16x8*)(R + t * 48 + ((c + t) % 6) * 8);
                _Float16* dst = rg ? k_h : q_h;
                *(f16x8*)(dst + (size_t)(bq * NN + nb + t) * DD + (col & 1023)) = v;
            }
        }
    }
    // pass 2: v chunks direct transposed scalar stores
#pragma unroll
    for (int nt = 0; nt < 3; ++nt) {
        int colbase = cwb + nt * 16;
        if ((colbase >> 10) == 2) {
            int fb = nt * 16 + lhi * 4;
            f32x4 b4 = *(const f32x4*)(bias + cwb + fb);
#pragma unroll
            for (int r = 0; r < 4; ++r) {
                int c1023 = (colbase + lhi * 4 + r) & 1023;
                int h = c1023 >> 6, dh = c1023 & 63;
                _Float16* vb = vt_h + ((size_t)((bq * HH + h) * DHH + dh)) * NN;
#pragma unroll
                for (int mt = 0; mt < 8; ++mt) {
                    int n = nb + mt * 16 + llo;
                    vb[n] = (_Float16)(acc[nt][mt][r] + b4[r]);
                }
            }
        }
    }
#undef STA
#undef STB
#undef RDA
#undef RDB
#undef MM
}

// ---------------- out-proj GEMM v2: 128x128 tile (R0-verified kloop<true,4> path) ----------------
__global__ __launch_bounds__(256) void gemm_out(const _Float16* __restrict__ A,
                                                const _Float16* __restrict__ Bt,
                                                const float* __restrict__ bias,
                                                float* __restrict__ Cf) {
    const int K = DD, N = DD;
    __shared__ __align__(16) _Float16 As[128 * 64];
    __shared__ __align__(16) _Float16 Bs[128 * 64];
    int id = blockIdx.x;
    int xcd = id & 7, j = id >> 3;            // 32 tiles per XCD chunk
    int bm = (xcd * 4 + (j >> 3)) * 128;      // 32 m-tiles = 8 xcd x 4
    int bn = (j & 7) * 128;                   // 8 n-tiles
    int tid = threadIdx.x;
    int wave = tid >> 6, lane = tid & 63;
    int wm = (wave >> 1) * 64, wn = (wave & 1) * 64;
    int lhi = lane >> 4, llo = lane & 15;

    f32x4 acc[4][4] = {};   // [nt][mt]

    int srow = wave * 32 + (lane >> 3);
    int scol = ((lane & 7) ^ (lane >> 3)) * 8;
    const _Float16* gA = A + (size_t)(bm + srow) * K + scol;
    const _Float16* gB = Bt + (size_t)(bn + srow) * K + scol;
    _Float16* lA = As + wave * 2048 + lane * 8;
    _Float16* lB = Bs + wave * 2048 + lane * 8;

    gemm_kloop<true, 4>(gA, gB, lA, lB, As, Bs, wm, wn, llo, lhi, K, acc);

#pragma unroll
    for (int nt = 0; nt < 4; ++nt) {
        int cbase = bn + wn + nt * 16 + lhi * 4;
        f32x4 b4 = *(const f32x4*)(bias + cbase);
#pragma unroll
        for (int mt = 0; mt < 4; ++mt) {
            int t = bm + wm + mt * 16 + llo;
            f32x4 v4;
#pragma unroll
            for (int r = 0; r < 4; ++r) v4[r] = acc[nt][mt][r] + b4[r];
            *(f32x4*)(Cf + (size_t)t * N + cbase) = v4;
        }
    }
}

// ---------------- windowed attention (R3-verified: QBLK=128, 8 waves, 512 blocks = exact 2/CU fill) ----------------
// Per block: K rows i0-64 .. i0+191 (256 rows), V same 256 tokens (+zero pad). Each wave w owns
// queries qrow=w*16+llo and computes only its 9 visible key-tiles (global tiles w..w+8).
// P overlay on Ks. Strides for <=2-way LDS aliasing (free): PP2=168, VP2=280.
#define PP2 168
#define VP2 280
__global__ __launch_bounds__(512, 4) void local_attn(const _Float16* __restrict__ q_h,
                                                     const _Float16* __restrict__ k_h,
                                                     const _Float16* __restrict__ vt_h,
                                                     _Float16* __restrict__ outh) {
    __shared__ __align__(16) _Float16 KsPs[128 * PP2];  // 43008 B: Ks[256*64]=32768 B overlaid by P
    __shared__ __align__(16) _Float16 Vt[64 * VP2];     // 35840 B
    _Float16* Ks = KsPs;
    _Float16* Ps = KsPs;
    int tid = threadIdx.x;
    int id = blockIdx.x;
    int xcd = id & 7, j = id >> 3;          // 64 j per xcd
    int i0 = (xcd * 2 + (j & 1)) * 128;     // 16 i-tiles = 8 xcd x 2
    int hb = j >> 1;
    int h = hb & 15, b = hb >> 4;

    int wave = tid >> 6, lane = tid & 63;   // 8 waves
    int llo = lane & 15, lhi = lane >> 4;

    // --- async K staging: rows jj = i0-64 .. i0+191 (OOR rows: mapped garbage, masked later) ---
    {
        int srow = lane >> 3;
        int chunk = ((lane & 7) ^ (lane >> 3)) * 8;
        const _Float16* kb = k_h + (size_t)(b * NN) * DD + h * DHH + chunk;
#pragma unroll
        for (int q = 0; q < 4; ++q) {
            int p = wave * 4 + q;            // 32 tiles of 8 rows
            int jj = i0 - 64 + p * 8 + srow;
            __builtin_amdgcn_global_load_lds(AS1(kb + (ptrdiff_t)jj * DD), AS3(Ks + p * 512 + lane * 8), 16, 0, 0);
        }
    }

    // --- V^T staging: 64 dh-rows x 256 tokens; zero pad cols 256..279 (read by w=7 PV, P=0 there) ---
    {
        const _Float16* vb = vt_h + (size_t)((b * HH + h) * DHH) * NN + (i0 - 64);
#pragma unroll
        for (int u = tid; u < 2048; u += 512) {      // 64 rows x 32 chunks
            int d = u >> 5, c = u & 31;
            f16x8 vv = *(const f16x8*)(vb + (ptrdiff_t)d * NN + c * 8);
            *(f16x8*)(Vt + d * VP2 + c * 8) = vv;
        }
        if (tid < 192) {                             // 64 rows x 3 pad chunks
            int d = tid / 3, c = tid % 3;
            f16x8 z = {};
            *(f16x8*)(Vt + d * VP2 + 256 + c * 8) = z;
        }
    }

    // --- Q fragments straight from global ---
    int qrow = wave * 16 + llo;
    int qi = i0 + qrow;
    const _Float16* qp = q_h + (size_t)(b * NN + qi) * DD + h * DHH;
    f16x8 qf0 = *(const f16x8*)(qp + lhi * 8);
    f16x8 qf1 = *(const f16x8*)(qp + 32 + lhi * 8);
    __syncthreads();

    // --- S^T = K @ Q^T over the wave's 9 visible key-tiles (global tile g = wave + mtl) ---
    float sc[9][4];
#pragma unroll
    for (int mtl = 0; mtl < 9; ++mtl) {
        const _Float16* kr = Ks + ((wave + mtl) * 16 + llo) * 64;   // row&7 == llo&7 -> same swizzle
        f16x8 kf0 = *(const f16x8*)(kr + ((lhi ^ (llo & 7)) * 8));
        f16x8 kf1 = *(const f16x8*)(kr + (((lhi + 4) ^ (llo & 7)) * 8));
        f32x4 a = {0.f, 0.f, 0.f, 0.f};
        a = __builtin_amdgcn_mfma_f32_16x16x32_f16(kf0, qf0, a, 0, 0, 0);
        a = __builtin_amdgcn_mfma_f32_16x16x32_f16(kf1, qf1, a, 0, 0, 0);
#pragma unroll
        for (int r = 0; r < 4; ++r) sc[mtl][r] = a[r];
    }
    __syncthreads();   // all waves done reading Ks; its LDS is now P's

    // --- masked softmax over the wave's 144 slots for query qi ---
    float m = -1e30f;
#pragma unroll
    for (int mtl = 0; mtl < 9; ++mtl)
#pragma unroll
        for (int r = 0; r < 4; ++r) {
            int sidx = (wave + mtl) * 16 + lhi * 4 + r;    // global staged slot
            int jj = i0 - 64 + sidx;
            int dj = jj - qi;
            bool valid = (jj >= 0) && (jj < NN) && (dj <= 64) && (dj >= -64);
            float v = valid ? sc[mtl][r] * SCALE : -1e30f;  // select: garbage never propagates
            sc[mtl][r] = v;
            m = fmaxf(m, v);
        }
    m = fmaxf(m, __shfl_xor(m, 16, 64));
    m = fmaxf(m, __shfl_xor(m, 32, 64));
    float l = 0.f;
#pragma unroll
    for (int mtl = 0; mtl < 9; ++mtl)
#pragma unroll
        for (int r = 0; r < 4; ++r) {
            float e = __expf(sc[mtl][r] - m);
            sc[mtl][r] = e;
            l += e;
        }
    l += __shfl_xor(l, 16, 64);
    l += __shfl_xor(l, 32, 64);
    float invl = 1.f / l;

    // --- write normalized P rows (own rows -> wave-local wait); pad cols 144..159 = 0 ---
#pragma unroll
    for (int mtl = 0; mtl < 9; ++mtl) {
        f16x4 pv;
#pragma unroll
        for (int r = 0; r < 4; ++r) pv[r] = (_Float16)(sc[mtl][r] * invl);
        *(f16x4*)(Ps + qrow * PP2 + mtl * 16 + lhi * 4) = pv;
    }
    {
        f16x4 z4 = {};
        *(f16x4*)(Ps + qrow * PP2 + 144 + lhi * 4) = z4;   // pad cols 144..159
    }
    __asm__ volatile("s_waitcnt lgkmcnt(0)" ::: "memory");  // wave-local P write->read

    // --- O = P @ V (V cols shifted by wave*16; pad P x pad V) ---
    f32x4 oacc[4] = {};
#pragma unroll
    for (int ks = 0; ks < 5; ++ks) {
        f16x8 pf = *(const f16x8*)(Ps + qrow * PP2 + ks * 32 + lhi * 8);
#pragma unroll
        for (int nt = 0; nt < 4; ++nt) {
            f16x8 vf = *(const f16x8*)(Vt + (nt * 16 + llo) * VP2 + wave * 16 + ks * 32 + lhi * 8);
            oacc[nt] = __builtin_amdgcn_mfma_f32_16x16x32_f16(pf, vf, oacc[nt], 0, 0, 0);
        }
    }

    // --- epilogue: col=llo=dh, row=lhi*4+r=query ---
    _Float16* orow = outh + (size_t)(b * NN) * DD + h * DHH;
#pragma unroll
    for (int nt = 0; nt < 4; ++nt)
#pragma unroll
        for (int r = 0; r < 4; ++r) {
            int q = wave * 16 + lhi * 4 + r;
            int d = nt * 16 + llo;
            orow[(size_t)(i0 + q) * DD + d] = (_Float16)oacc[nt][r];
        }
}

// ---------------- launch ----------------
extern "C" void kernel_launch(void* const* d_in, const int* in_sizes, int n_in,
                              void* d_out, int out_size, void* d_ws, size_t ws_size,
                              hipStream_t stream) {
    const float* x    = (const float*)d_in[0];
    const float* Wqkv = (const float*)d_in[1];
    const float* bqkv = (const float*)d_in[2];
    const float* Wout = (const float*)d_in[3];
    const float* bout = (const float*)d_in[4];
    float* out = (float*)d_out;

    char* ws = (char*)d_ws;
    _Float16* x_h    = (_Float16*)(ws);                              //  8 MB [4096][1024]
    _Float16* Wqkv_t = (_Float16*)(ws + (size_t)8  * 1024 * 1024);   //  6 MB [3072][1024]
    _Float16* Wout_t = (_Float16*)(ws + (size_t)14 * 1024 * 1024);   //  2 MB [1024][1024]
    _Float16* q_h    = (_Float16*)(ws + (size_t)16 * 1024 * 1024);   //  8 MB [2][2048][1024]
    _Float16* k_h    = (_Float16*)(ws + (size_t)24 * 1024 * 1024);   //  8 MB [2][2048][1024]
    _Float16* vt_h   = (_Float16*)(ws + (size_t)32 * 1024 * 1024);   //  8 MB [2*16*64][2048]
    _Float16* attn_h = (_Float16*)(ws + (size_t)40 * 1024 * 1024);   //  8 MB [4096][1024]

    prep<<<6144, 256, 0, stream>>>(x, x_h, Wqkv, Wqkv_t, Wout, Wout_t);

    gemm_qkv<<<256, 512, 0, stream>>>(x_h, Wqkv_t, bqkv, q_h, k_h, vt_h);

    local_attn<<<512, 512, 0, stream>>>(q_h, k_h, vt_h, attn_h);

    gemm_out<<<256, 256, 0, stream>>>(attn_h, Wout_t, bout, out);
}

// Round 12
// 144.913 us; speedup vs baseline: 1.7845x; 1.0032x over previous
//
#include <hip/hip_runtime.h>
#include <hip/hip_bf16.h>
#include <cstdint>
#include <cstddef>

// Problem constants (B=2, N=2048, D=1024, H=16, DH=64, window +-64)
#define BB 2
#define NN 2048
#define DD 1024
#define HH 16
#define DHH 64
#define SCALE 0.125f

typedef _Float16 f16x8 __attribute__((ext_vector_type(8)));
typedef _Float16 f16x4 __attribute__((ext_vector_type(4)));
typedef float f32x4 __attribute__((ext_vector_type(4)));

#define AS1(p) ((__attribute__((address_space(1))) void*)(p))
#define AS3(p) ((__attribute__((address_space(3))) void*)(p))

// ---------------- fused prep: x cast + both weight transposes, one launch ----------------
__global__ __launch_bounds__(256) void prep(const float* __restrict__ x, _Float16* __restrict__ x_h,
                                            const float* __restrict__ Wqkv, _Float16* __restrict__ Wqkv_t,
                                            const float* __restrict__ Wout, _Float16* __restrict__ Wout_t) {
    __shared__ float tile[32][33];
    int bx = blockIdx.x, tid = threadIdx.x;
    if (bx < 2048) {
        int i = bx * 2048 + tid * 8;
        f32x4 a = *(const f32x4*)(x + i);
        f32x4 b = *(const f32x4*)(x + i + 4);
        f16x8 o;
        o[0] = (_Float16)a[0]; o[1] = (_Float16)a[1]; o[2] = (_Float16)a[2]; o[3] = (_Float16)a[3];
        o[4] = (_Float16)b[0]; o[5] = (_Float16)b[1]; o[6] = (_Float16)b[2]; o[7] = (_Float16)b[3];
        *(f16x8*)(x_h + i) = o;
        return;
    }
    const float* in; _Float16* out; int C, tc, tr;
    if (bx < 5120) { int t = bx - 2048; C = 3 * DD; in = Wqkv; out = Wqkv_t; tc = t % 96; tr = t / 96; }
    else           { int t = bx - 5120; C = DD;     in = Wout; out = Wout_t; tc = t % 32; tr = t / 32; }
    int R = DD;
    int txx = tid & 31, ty = tid >> 5;
    int r0 = tr * 32, c0 = tc * 32;
#pragma unroll
    for (int i = 0; i < 32; i += 8)
        tile[ty + i][txx] = in[(size_t)(r0 + ty + i) * C + (c0 + txx)];
    __syncthreads();
#pragma unroll
    for (int i = 0; i < 32; i += 8)
        out[(size_t)(c0 + ty + i) * R + (r0 + txx)] = (_Float16)tile[txx][ty + i];
}

// ---------------- shared K-loop body (R6 family) — used by gemm_out only ----------------
template <bool SWAP, int MT>
__device__ __forceinline__ void gemm_kloop(const _Float16* __restrict__ gA,
                                           const _Float16* __restrict__ gB,
                                           _Float16* lA, _Float16* lB,
                                           const _Float16* As, const _Float16* Bs,
                                           int wm, int wn, int llo, int lhi, int K,
                                           f32x4 acc[][MT > 4 ? MT : 4]) {
    for (int k0 = 0; k0 < K; k0 += 64) {
        __syncthreads();
#pragma unroll
        for (int p = 0; p < MT; ++p)
            __builtin_amdgcn_global_load_lds(AS1(gA + (size_t)p * 8 * K + k0), AS3(lA + p * 512), 16, 0, 0);
#pragma unroll
        for (int p = 0; p < 4; ++p)
            __builtin_amdgcn_global_load_lds(AS1(gB + (size_t)p * 8 * K + k0), AS3(lB + p * 512), 16, 0, 0);
        __syncthreads();

#pragma unroll
        for (int ks = 0; ks < 2; ++ks) {
            f16x8 af[MT], bf[4];
            int swz = (((ks * 4 + lhi) ^ (llo & 7)) * 8);
#pragma unroll
            for (int mt = 0; mt < MT; ++mt)
                af[mt] = *(const f16x8*)(As + (wm + mt * 16 + llo) * 64 + swz);
#pragma unroll
            for (int nt = 0; nt < 4; ++nt)
                bf[nt] = *(const f16x8*)(Bs + (wn + nt * 16 + llo) * 64 + swz);
            if (SWAP) {
#pragma unroll
                for (int nt = 0; nt < 4; ++nt)
#pragma unroll
                    for (int mt = 0; mt < MT; ++mt)
                        acc[nt][mt] = __builtin_amdgcn_mfma_f32_16x16x32_f16(bf[nt], af[mt], acc[nt][mt], 0, 0, 0);
            } else {
#pragma unroll
                for (int mt = 0; mt < MT; ++mt)
#pragma unroll
                    for (int nt = 0; nt < 4; ++nt)
                        acc[mt][nt] = __builtin_amdgcn_mfma_f32_16x16x32_f16(af[mt], bf[nt], acc[mt][nt], 0, 0, 0);
            }
        }
    }
}

// ---------------- QKV GEMM v7 (R9-verified): 256x192 tile, 256 blocks = exact CU fill, all-SWAP ----------------
__global__ __launch_bounds__(512, 2) void gemm_qkv(const _Float16* __restrict__ A,
                                                   const _Float16* __restrict__ Bt,
                                                   const float* __restrict__ bias,
                                                   _Float16* __restrict__ q_h,
                                                   _Float16* __restrict__ k_h,
                                                   _Float16* __restrict__ vt_h) {
    __shared__ __align__(16) _Float16 As[2 * 16384];   // 64 KiB: 2 x [256][64]
    __shared__ __align__(16) _Float16 Bs[2 * 12288];   // 48 KiB: 2 x [192][64]
    int id = blockIdx.x;
    int xcd = id & 7, jj = id >> 3;                    // 32 tiles per XCD chunk
    int mtile = (xcd >> 1) * 4 + (jj >> 3);            // 16 M-tiles = 4 groups of 4
    int ntile = (xcd & 1) * 8 + (jj & 7);              // 16 N-tiles = 2 groups of 8
    int bm = mtile * 256, bn = ntile * 192;

    int tid = threadIdx.x;
    int wave = tid >> 6, lane = tid & 63;
    int llo = lane & 15, lhi = lane >> 4;
    int wm = (wave >> 2) * 128, wn = (wave & 3) * 48;  // per-wave 128x48 output tile
    int l8 = lane >> 3;
    int gchunk = ((lane & 7) ^ l8) * 8;                // inverse-swizzled source chunk

    int rAu = wm + (wave & 3) * 16;                    // A staging rows (as v6)
    const _Float16* gA = A + (size_t)(bm + rAu + l8) * DD + gchunk;
    _Float16* lA = As + rAu * 64 + lane * 8;
    const _Float16* gB = Bt + (size_t)(bn + wave * 8 + l8) * DD + gchunk;   // B: wave w covers rows g*64+w*8..+8
    _Float16* lB = Bs + wave * 512 + lane * 8;

#define STA(H, C, T, U) __builtin_amdgcn_global_load_lds( \
        AS1(gA + (size_t)((H) * 64 + (C) * 8) * DD + (T) * 64), \
        AS3(lA + (U) * 16384 + ((H) * 64 + (C) * 8) * 64), 16, 0, 0)
#define STB(G, T, U) __builtin_amdgcn_global_load_lds( \
        AS1(gB + (size_t)((G) * 64) * DD + (T) * 64), \
        AS3(lB + (U) * 12288 + (G) * 4096), 16, 0, 0)
#define RDA(MT, KS, U) (*(const f16x8*)(As + (U) * 16384 + (wm + (MT) * 16 + llo) * 64 + ((((KS) * 4 + lhi) ^ (llo & 7)) * 8)))
#define RDB(NT, KS, U) (*(const f16x8*)(Bs + (U) * 12288 + (wn + (NT) * 16 + llo) * 64 + ((((KS) * 4 + lhi) ^ (llo & 7)) * 8)))
#define MM(MT, NT, KS) \
        acc[NT][MT] = __builtin_amdgcn_mfma_f32_16x16x32_f16(bf[NT][KS], af[(MT) & 3][KS], acc[NT][MT], 0, 0, 0)

    f32x4 acc[3][8] = {};        // [nt][mt] = C^T fragments
    f16x8 af[4][2], bf[3][2];

    // prologue: K-tile 0 into buf 0, FIFO order = consumption order: A0(2), B(3), A1(2)
    STA(0, 0, 0, 0); STA(0, 1, 0, 0);
    STB(0, 0, 0); STB(1, 0, 0); STB(2, 0, 0);
    STA(1, 0, 0, 0); STA(1, 1, 0, 0);
    asm volatile("s_waitcnt vmcnt(2)" ::: "memory");   // A0,B landed; A1 in flight
    __builtin_amdgcn_s_barrier();

#pragma unroll 1
    for (int t = 0; t < 15; ++t) {
        int u = t & 1, nu = u ^ 1;
        // ---- P1: read A0 (mt0-3) + B (nt0-2); stage A0'(2)+B'(3); 24 MFMA
#pragma unroll
        for (int mt = 0; mt < 4; ++mt) { af[mt][0] = RDA(mt, 0, u); af[mt][1] = RDA(mt, 1, u); }
#pragma unroll
        for (int nt = 0; nt < 3; ++nt) { bf[nt][0] = RDB(nt, 0, u); bf[nt][1] = RDB(nt, 1, u); }
        STA(0, 0, t + 1, nu); STA(0, 1, t + 1, nu);
        STB(0, t + 1, nu); STB(1, t + 1, nu); STB(2, t + 1, nu);
        __builtin_amdgcn_s_barrier();
        asm volatile("s_waitcnt lgkmcnt(0)" ::: "memory");
        __builtin_amdgcn_s_setprio(1);
#pragma unroll
        for (int ks = 0; ks < 2; ++ks)
#pragma unroll
            for (int mt = 0; mt < 4; ++mt) { MM(mt, 0, ks); MM(mt, 1, ks); MM(mt, 2, ks); }
        __builtin_amdgcn_s_setprio(0);
        asm volatile("s_waitcnt vmcnt(5)" ::: "memory");   // A1(t) landed (issued P2(t-1))
        __builtin_amdgcn_s_barrier();
        // ---- P2: read A1 (mt4-7); stage A1'(2); 24 MFMA
#pragma unroll
        for (int mt = 0; mt < 4; ++mt) { af[mt][0] = RDA(mt + 4, 0, u); af[mt][1] = RDA(mt + 4, 1, u); }
        STA(1, 0, t + 1, nu); STA(1, 1, t + 1, nu);
        __builtin_amdgcn_s_barrier();
        asm volatile("s_waitcnt lgkmcnt(0)" ::: "memory");
        __builtin_amdgcn_s_setprio(1);
#pragma unroll
        for (int ks = 0; ks < 2; ++ks)
#pragma unroll
            for (int mt = 4; mt < 8; ++mt) { MM(mt, 0, ks); MM(mt, 1, ks); MM(mt, 2, ks); }
        __builtin_amdgcn_s_setprio(0);
        asm volatile("s_waitcnt vmcnt(2)" ::: "memory");   // A0',B'(t+1) landed
        __builtin_amdgcn_s_barrier();
    }

    // ---- peeled K-tile 15 (buf 1): drain 2 -> 0
    {
#pragma unroll
        for (int mt = 0; mt < 4; ++mt) { af[mt][0] = RDA(mt, 0, 1); af[mt][1] = RDA(mt, 1, 1); }
#pragma unroll
        for (int nt = 0; nt < 3; ++nt) { bf[nt][0] = RDB(nt, 0, 1); bf[nt][1] = RDB(nt, 1, 1); }
        asm volatile("s_waitcnt lgkmcnt(0)" ::: "memory");
        __builtin_amdgcn_s_setprio(1);
#pragma unroll
        for (int ks = 0; ks < 2; ++ks)
#pragma unroll
            for (int mt = 0; mt < 4; ++mt) { MM(mt, 0, ks); MM(mt, 1, ks); MM(mt, 2, ks); }
        __builtin_amdgcn_s_setprio(0);
        asm volatile("s_waitcnt vmcnt(0)" ::: "memory");   // A1(15) landed
        __builtin_amdgcn_s_barrier();
#pragma unroll
        for (int mt = 0; mt < 4; ++mt) { af[mt][0] = RDA(mt + 4, 0, 1); af[mt][1] = RDA(mt + 4, 1, 1); }
        asm volatile("s_waitcnt lgkmcnt(0)" ::: "memory");
        __builtin_amdgcn_s_setprio(1);
#pragma unroll
        for (int ks = 0; ks < 2; ++ks)
#pragma unroll
            for (int mt = 4; mt < 8; ++mt) { MM(mt, 0, ks); MM(mt, 1, ks); MM(mt, 2, ks); }
        __builtin_amdgcn_s_setprio(0);
    }

    // ---- epilogue: per-chunk region; q/k via LDS restage + f16x8 rows; v direct transposed ----
    __builtin_amdgcn_s_barrier();      // all waves done with K-loop LDS reads; As/Bs now dead
    _Float16* R = (wave < 4) ? (As + wave * 6144) : (Bs + (wave - 4) * 6144);  // 12 KB/wave
    int bq = bm >> 11;                 // batch (256-tile never crosses n=2048)
    int nb = (bm & 2047) + wm;         // wave's first token within batch
    int cwb = bn + wn;                 // wave's absolute first output col (0..3072)

    // pass 1a: restage [tok 128][feat 48], slot = (chunk + t) % 6 (rotate; chunk 0..5)
#pragma unroll
    for (int nt = 0; nt < 3; ++nt) {
        int fb = nt * 16 + lhi * 4;                    // 0..44
        f32x4 b4 = *(const f32x4*)(bias + cwb + fb);
        int chunk = fb >> 3, off = fb & 7;             // off = 0 or 4
#pragma unroll
        for (int mt = 0; mt < 8; ++mt) {
            int t = mt * 16 + llo;
            f16x4 v4;
#pragma unroll
            for (int r = 0; r < 4; ++r) v4[r] = (_Float16)(acc[nt][mt][r] + b4[r]);
            *(f16x4*)(R + t * 48 + ((chunk + t) % 6) * 8 + off) = v4;
        }
    }
    asm volatile("s_waitcnt lgkmcnt(0)" ::: "memory");   // wave-local write->read
    // pass 1b: coalesced f16x8 row stores for q/k chunks
#pragma unroll
    for (int it = 0; it < 16; ++it) {
        int t = it * 8 + l8;
        int c = lane & 7;
        if (c < 6) {
            int col = cwb + c * 8;
            int rg = col >> 10;
            if (rg < 2) {
                f16x8 v = *(const f16x8*)(R + t * 48 + ((c + t) % 6) * 8);
                _Float16* dst = rg ? k_h : q_h;
                *(f16x8*)(dst + (size_t)(bq * NN + nb + t) * DD + (col & 1023)) = v;
            }
        }
    }
    // pass 2: v chunks direct transposed scalar stores
#pragma unroll
    for (int nt = 0; nt < 3; ++nt) {
        int colbase = cwb + nt * 16;
        if ((colbase >> 10) == 2) {
            int fb = nt * 16 + lhi * 4;
            f32x4 b4 = *(const f32x4*)(bias + cwb + fb);
#pragma unroll
            for (int r = 0; r < 4; ++r) {
                int c1023 = (colbase + lhi * 4 + r) & 1023;
                int h = c1023 >> 6, dh = c1023 & 63;
                _Float16* vb = vt_h + ((size_t)((bq * HH + h) * DHH + dh)) * NN;
#pragma unroll
                for (int mt = 0; mt < 8; ++mt) {
                    int n = nb + mt * 16 + llo;
                    vb[n] = (_Float16)(acc[nt][mt][r] + b4[r]);
                }
            }
        }
    }
#undef STA
#undef STB
#undef RDA
#undef RDB
#undef MM
}

// ---------------- out-proj GEMM v2: 128x128 tile (R0-verified kloop<true,4> path) ----------------
__global__ __launch_bounds__(256) void gemm_out(const _Float16* __restrict__ A,
                                                const _Float16* __restrict__ Bt,
                                                const float* __restrict__ bias,
                                                float* __restrict__ Cf) {
    const int K = DD, N = DD;
    __shared__ __align__(16) _Float16 As[128 * 64];
    __shared__ __align__(16) _Float16 Bs[128 * 64];
    int id = blockIdx.x;
    int xcd = id & 7, j = id >> 3;            // 32 tiles per XCD chunk
    int bm = (xcd * 4 + (j >> 3)) * 128;      // 32 m-tiles = 8 xcd x 4
    int bn = (j & 7) * 128;                   // 8 n-tiles
    int tid = threadIdx.x;
    int wave = tid >> 6, lane = tid & 63;
    int wm = (wave >> 1) * 64, wn = (wave & 1) * 64;
    int lhi = lane >> 4, llo = lane & 15;

    f32x4 acc[4][4] = {};   // [nt][mt]

    int srow = wave * 32 + (lane >> 3);
    int scol = ((lane & 7) ^ (lane >> 3)) * 8;
    const _Float16* gA = A + (size_t)(bm + srow) * K + scol;
    const _Float16* gB = Bt + (size_t)(bn + srow) * K + scol;
    _Float16* lA = As + wave * 2048 + lane * 8;
    _Float16* lB = Bs + wave * 2048 + lane * 8;

    gemm_kloop<true, 4>(gA, gB, lA, lB, As, Bs, wm, wn, llo, lhi, K, acc);

#pragma unroll
    for (int nt = 0; nt < 4; ++nt) {
        int cbase = bn + wn + nt * 16 + lhi * 4;
        f32x4 b4 = *(const f32x4*)(bias + cbase);
#pragma unroll
        for (int mt = 0; mt < 4; ++mt) {
            int t = bm + wm + mt * 16 + llo;
            f32x4 v4;
#pragma unroll
            for (int r = 0; r < 4; ++r) v4[r] = acc[nt][mt][r] + b4[r];
            *(f32x4*)(Cf + (size_t)t * N + cbase) = v4;
        }
    }
}

// ---------------- windowed attention (R10-verified: QBLK=128, 8 waves, 512 blocks = exact 2/CU fill) ----------------
#define PP2 168
#define VP2 280
__global__ __launch_bounds__(512, 4) void local_attn(const _Float16* __restrict__ q_h,
                                                     const _Float16* __restrict__ k_h,
                                                     const _Float16* __restrict__ vt_h,
                                                     _Float16* __restrict__ outh) {
    __shared__ __align__(16) _Float16 KsPs[128 * PP2];  // 43008 B: Ks[256*64]=32768 B overlaid by P
    __shared__ __align__(16) _Float16 Vt[64 * VP2];     // 35840 B
    _Float16* Ks = KsPs;
    _Float16* Ps = KsPs;
    int tid = threadIdx.x;
    int id = blockIdx.x;
    int xcd = id & 7, j = id >> 3;          // 64 j per xcd
    int i0 = (xcd * 2 + (j & 1)) * 128;     // 16 i-tiles = 8 xcd x 2
    int hb = j >> 1;
    int h = hb & 15, b = hb >> 4;

    int wave = tid >> 6, lane = tid & 63;   // 8 waves
    int llo = lane & 15, lhi = lane >> 4;

    // --- async K staging: rows jj = i0-64 .. i0+191 (OOR rows: mapped garbage, masked later) ---
    {
        int srow = lane >> 3;
        int chunk = ((lane & 7) ^ (lane >> 3)) * 8;
        const _Float16* kb = k_h + (size_t)(b * NN) * DD + h * DHH + chunk;
#pragma unroll
        for (int q = 0; q < 4; ++q) {
            int p = wave * 4 + q;            // 32 tiles of 8 rows
            int jj = i0 - 64 + p * 8 + srow;
            __builtin_amdgcn_global_load_lds(AS1(kb + (ptrdiff_t)jj * DD), AS3(Ks + p * 512 + lane * 8), 16, 0, 0);
        }
    }

    // --- V^T staging: 64 dh-rows x 256 tokens; zero pad cols 256..279 (read by w=7 PV, P=0 there) ---
    {
        const _Float16* vb = vt_h + (size_t)((b * HH + h) * DHH) * NN + (i0 - 64);
#pragma unroll
        for (int u = tid; u < 2048; u += 512) {      // 64 rows x 32 chunks
            int d = u >> 5, c = u & 31;
            f16x8 vv = *(const f16x8*)(vb + (ptrdiff_t)d * NN + c * 8);
            *(f16x8*)(Vt + d * VP2 + c * 8) = vv;
        }
        if (tid < 192) {                             // 64 rows x 3 pad chunks
            int d = tid / 3, c = tid % 3;
            f16x8 z = {};
            *(f16x8*)(Vt + d * VP2 + 256 + c * 8) = z;
        }
    }

    // --- Q fragments straight from global ---
    int qrow = wave * 16 + llo;
    int qi = i0 + qrow;
    const _Float16* qp = q_h + (size_t)(b * NN + qi) * DD + h * DHH;
    f16x8 qf0 = *(const f16x8*)(qp + lhi * 8);
    f16x8 qf1 = *(const f16x8*)(qp + 32 + lhi * 8);
    __syncthreads();

    // --- S^T = K @ Q^T over the wave's 9 visible key-tiles (global tile g = wave + mtl) ---
    float sc[9][4];
#pragma unroll
    for (int mtl = 0; mtl < 9; ++mtl) {
        const _Float16* kr = Ks + ((wave + mtl) * 16 + llo) * 64;   // row&7 == llo&7 -> same swizzle
        f16x8 kf0 = *(const f16x8*)(kr + ((lhi ^ (llo & 7)) * 8));
        f16x8 kf1 = *(const f16x8*)(kr + (((lhi + 4) ^ (llo & 7)) * 8));
        f32x4 a = {0.f, 0.f, 0.f, 0.f};
        a = __builtin_amdgcn_mfma_f32_16x16x32_f16(kf0, qf0, a, 0, 0, 0);
        a = __builtin_amdgcn_mfma_f32_16x16x32_f16(kf1, qf1, a, 0, 0, 0);
#pragma unroll
        for (int r = 0; r < 4; ++r) sc[mtl][r] = a[r];
    }
    __syncthreads();   // all waves done reading Ks; its LDS is now P's

    // --- masked softmax over the wave's 144 slots for query qi ---
    float m = -1e30f;
#pragma unroll
    for (int mtl = 0; mtl < 9; ++mtl)
#pragma unroll
        for (int r = 0; r < 4; ++r) {
            int sidx = (wave + mtl) * 16 + lhi * 4 + r;    // global staged slot
            int jj = i0 - 64 + sidx;
            int dj = jj - qi;
            bool valid = (jj >= 0) && (jj < NN) && (dj <= 64) && (dj >= -64);
            float v = valid ? sc[mtl][r] * SCALE : -1e30f;  // select: garbage never propagates
            sc[mtl][r] = v;
            m = fmaxf(m, v);
        }
    m = fmaxf(m, __shfl_xor(m, 16, 64));
    m = fmaxf(m, __shfl_xor(m, 32, 64));
    float l = 0.f;
#pragma unroll
    for (int mtl = 0; mtl < 9; ++mtl)
#pragma unroll
        for (int r = 0; r < 4; ++r) {
            float e = __expf(sc[mtl][r] - m);
            sc[mtl][r] = e;
            l += e;
        }
    l += __shfl_xor(l, 16, 64);
    l += __shfl_xor(l, 32, 64);
    float invl = 1.f / l;

    // --- write normalized P rows (own rows -> wave-local wait); pad cols 144..159 = 0 ---
#pragma unroll
    for (int mtl = 0; mtl < 9; ++mtl) {
        f16x4 pv;
#pragma unroll
        for (int r = 0; r < 4; ++r) pv[r] = (_Float16)(sc[mtl][r] * invl);
        *(f16x4*)(Ps + qrow * PP2 + mtl * 16 + lhi * 4) = pv;
    }
    {
        f16x4 z4 = {};
        *(f16x4*)(Ps + qrow * PP2 + 144 + lhi * 4) = z4;   // pad cols 144..159
    }
    __asm__ volatile("s_waitcnt lgkmcnt(0)" ::: "memory");  // wave-local P write->read

    // --- O = P @ V (V cols shifted by wave*16; pad P x pad V) ---
    f32x4 oacc[4] = {};
#pragma unroll
    for (int ks = 0; ks < 5; ++ks) {
        f16x8 pf = *(const f16x8*)(Ps + qrow * PP2 + ks * 32 + lhi * 8);
#pragma unroll
        for (int nt = 0; nt < 4; ++nt) {
            f16x8 vf = *(const f16x8*)(Vt + (nt * 16 + llo) * VP2 + wave * 16 + ks * 32 + lhi * 8);
            oacc[nt] = __builtin_amdgcn_mfma_f32_16x16x32_f16(pf, vf, oacc[nt], 0, 0, 0);
        }
    }

    // --- epilogue: col=llo=dh, row=lhi*4+r=query ---
    _Float16* orow = outh + (size_t)(b * NN) * DD + h * DHH;
#pragma unroll
    for (int nt = 0; nt < 4; ++nt)
#pragma unroll
        for (int r = 0; r < 4; ++r) {
            int q = wave * 16 + lhi * 4 + r;
            int d = nt * 16 + llo;
            orow[(size_t)(i0 + q) * DD + d] = (_Float16)oacc[nt][r];
        }
}

// ---------------- launch ----------------
extern "C" void kernel_launch(void* const* d_in, const int* in_sizes, int n_in,
                              void* d_out, int out_size, void* d_ws, size_t ws_size,
                              hipStream_t stream) {
    const float* x    = (const float*)d_in[0];
    const float* Wqkv = (const float*)d_in[1];
    const float* bqkv = (const float*)d_in[2];
    const float* Wout = (const float*)d_in[3];
    const float* bout = (const float*)d_in[4];
    float* out = (float*)d_out;

    char* ws = (char*)d_ws;
    _Float16* x_h    = (_Float16*)(ws);                              //  8 MB [4096][1024]
    _Float16* Wqkv_t = (_Float16*)(ws + (size_t)8  * 1024 * 1024);   //  6 MB [3072][1024]
    _Float16* Wout_t = (_Float16*)(ws + (size_t)14 * 1024 * 1024);   //  2 MB [1024][1024]
    _Float16* q_h    = (_Float16*)(ws + (size_t)16 * 1024 * 1024);   //  8 MB [2][2048][1024]
    _Float16* k_h    = (_Float16*)(ws + (size_t)24 * 1024 * 1024);   //  8 MB [2][2048][1024]
    _Float16* vt_h   = (_Float16*)(ws + (size_t)32 * 1024 * 1024);   //  8 MB [2*16*64][2048]
    _Float16* attn_h = (_Float16*)(ws + (size_t)40 * 1024 * 1024);   //  8 MB [4096][1024]

    prep<<<6144, 256, 0, stream>>>(x, x_h, Wqkv, Wqkv_t, Wout, Wout_t);

    gemm_qkv<<<256, 512, 0, stream>>>(x_h, Wqkv_t, bqkv, q_h, k_h, vt_h);

    local_attn<<<512, 512, 0, stream>>>(q_h, k_h, vt_h, attn_h);

    gemm_out<<<256, 256, 0, stream>>>(attn_h, Wout_t, bout, out);
}